// Round 7
// baseline (167.894 us; speedup 1.0000x reference)
//
#include <hip/hip_runtime.h>
#include <hip/hip_bf16.h>
#include <math.h>

#define NPIX 4096   // 64*64
#define DIMC 48
#define NB 2
#define SPLIT 4

typedef __attribute__((ext_vector_type(8))) short short8;
typedef __attribute__((ext_vector_type(4))) short short4s;
typedef __attribute__((ext_vector_type(4))) float floatx4;

static __device__ inline short f2bf(float f) {
    union { float f; unsigned u; } v; v.f = f;
    unsigned r = (v.u + 0x7FFFu + ((v.u >> 16) & 1u)) >> 16;
    return (short)r;
}
static __device__ inline float bf2f(short s) {
    union { unsigned u; float f; } v;
    v.u = ((unsigned)(unsigned short)s) << 16;
    return v.f;
}

// depthwise 3x3 tap sum at (y, gx) for channel plane ip (bf16), weights wp[9]
static __device__ inline float dw3_at(const short* __restrict__ ip,
                                      const float* __restrict__ wp,
                                      int gx, int y, float acc) {
#pragma unroll
    for (int dy = -1; dy <= 1; dy++) {
        int yy = y + dy;
        if ((unsigned)yy < 64u) {
#pragma unroll
            for (int dx = -1; dx <= 1; dx++) {
                int xx = gx + dx;
                if ((unsigned)xx < 64u)
                    acc += bf2f(ip[yy * 64 + xx]) * wp[(dy + 1) * 3 + (dx + 1)];
            }
        }
    }
    return acc;
}

// ============ K0: prep bf16 B-layout weights (rows padded to 64 k, zeros) ======
__global__ void k_prepw(const float* __restrict__ qkvw, const float* __restrict__ fiw,
                        const float* __restrict__ fow, const float* __restrict__ projw,
                        short* __restrict__ qkvwbf, short* __restrict__ fiwbf,
                        short* __restrict__ fowbf, short* __restrict__ projwbf) {
    int idx = blockIdx.x * 256 + threadIdx.x;
    if (idx < 144 * 64) {
        int o = idx >> 6, c = idx & 63;
        qkvwbf[idx] = (c < 48) ? f2bf(qkvw[o * 48 + c]) : (short)0;
        return;
    }
    idx -= 144 * 64;
    if (idx < 192 * 64) {
        int o = idx >> 6, c = idx & 63;
        fiwbf[idx] = (c < 48) ? f2bf(fiw[o * 48 + c]) : (short)0;
        return;
    }
    idx -= 192 * 64;
    if (idx < 48 * 96) {
        fowbf[idx] = f2bf(fow[idx]);
        return;
    }
    idx -= 48 * 96;
    if (idx < 48 * 64) {
        int o = idx >> 6, c = idx & 63;
        projwbf[idx] = (c < 48) ? f2bf(projw[o * 48 + c]) : (short)0;
    }
}

// ============ K1/K5: LayerNorm + 1x1 conv (MFMA), no halo ======================
// grid (128, NB), block 256. 32 px per block. out: bf16 [b][OC][4096].
__global__ __launch_bounds__(256) void k_ln_conv_mfma(
    const float* __restrict__ xin, const float* __restrict__ lw, const float* __restrict__ lb,
    const short* __restrict__ wbf, const float* __restrict__ cb,
    short* __restrict__ outbf, int OC)
{
    int px0 = blockIdx.x * 32;
    int b = blockIdx.y;
    int t = threadIdx.x;
    int w = t >> 6, lane = t & 63, l15 = lane & 15, quad = lane >> 4;

    __shared__ float psum[8][32], psq[8][32];
    __shared__ float muS[32], rsS[32];
    __shared__ short xnbf[32][72];

    int px = t & 31, g = t >> 5;     // 8 groups x 6 channels
    // zero the k-pad (c=48..63): each thread one dword
    *(unsigned*)&xnbf[px][48 + g * 2] = 0u;

    float v[6];
    float s = 0.f, sq = 0.f;
#pragma unroll
    for (int i = 0; i < 6; i++) {
        v[i] = xin[((size_t)b * 48 + g * 6 + i) * (size_t)NPIX + px0 + px];
        s += v[i]; sq += v[i] * v[i];
    }
    psum[g][px] = s; psq[g][px] = sq;
    __syncthreads();
    if (t < 32) {
        float ss = 0.f, qq = 0.f;
#pragma unroll
        for (int i = 0; i < 8; i++) { ss += psum[i][t]; qq += psq[i][t]; }
        float mu = ss * (1.f / 48.f);
        float var = qq * (1.f / 48.f) - mu * mu;
        muS[t] = mu; rsS[t] = rsqrtf(var + 1e-5f);
    }
    __syncthreads();
    {
        float mu = muS[px], rs = rsS[px];
#pragma unroll
        for (int i = 0; i < 6; i++) {
            int c = g * 6 + i;
            xnbf[px][c] = f2bf((v[i] - mu) * rs * lw[c] + lb[c]);
        }
    }
    __syncthreads();
    floatx4 zf = {0.f, 0.f, 0.f, 0.f};
    int oct = OC >> 4;
    int njobs = 2 * oct;
    for (int job = w; job < njobs; job += 4) {
        int pt = job / oct, ot = job % oct;
        short8 a0 = *(const short8*)&xnbf[pt * 16 + l15][quad * 8];
        short8 a1 = *(const short8*)&xnbf[pt * 16 + l15][32 + quad * 8];
        const short* wb = wbf + (ot * 16 + l15) * 64;
        short8 b0 = *(const short8*)(wb + quad * 8);
        short8 b1 = *(const short8*)(wb + 32 + quad * 8);
        floatx4 c = __builtin_amdgcn_mfma_f32_16x16x32_bf16(a0, b0, zf, 0, 0, 0);
        c = __builtin_amdgcn_mfma_f32_16x16x32_bf16(a1, b1, c, 0, 0, 0);
        int oc = ot * 16 + l15;
        float bi = cb[oc];
        short4s st;
#pragma unroll
        for (int r = 0; r < 4; r++) st[r] = f2bf(c[r] + bi);
        *(short4s*)(outbf + ((size_t)b * OC + oc) * (size_t)NPIX + px0 + pt * 16 + quad * 4) = st;
    }
}

// ============ K2: dw3 on qkv_pre + l2norm/temp + bf16 MFMA pack ================
// grid (4, 64, NB), block 256. 16 px (one row segment) per block.
// Qbf,Kbf: [bh][4096][32] row-major. Vbf: [bh][32][4096] keys PERMUTED within
// each 32-block: key r -> pos (r&15)*2 + (r>>4).
__global__ __launch_bounds__(256) void k_dw3heads(
    const short* __restrict__ qkv_pre, const float* __restrict__ dww,
    const float* __restrict__ dwb, const float* __restrict__ temp,
    short* __restrict__ Qbf, short* __restrict__ Kbf, short* __restrict__ Vbf)
{
    int px0 = blockIdx.x * 16;
    int y = blockIdx.y, b = blockIdx.z;
    int t = threadIdx.x;
    __shared__ float q2[16][148];

    int px = t & 15, g = t >> 4;   // 16 groups x 9 channels
    int gx = px0 + px;
    const short* base = qkv_pre + (size_t)b * 144 * NPIX;
    for (int i = 0; i < 9; i++) {
        int c = g * 9 + i;
        q2[px][c] = dw3_at(base + (size_t)c * NPIX, dww + c * 9, gx, y, dwb[c]);
    }
    __syncthreads();
    if (t < 32) {
        int hpx = t & 15, h = t >> 4;
        int n = y * 64 + px0 + hpx;
        int bh = b * 2 + h;
        float q[24], k[24], vv[24]; float sqs = 0.f, sks = 0.f;
#pragma unroll
        for (int c = 0; c < 24; c++) {
            q[c] = q2[hpx][h * 24 + c];       sqs += q[c] * q[c];
            k[c] = q2[hpx][48 + h * 24 + c];  sks += k[c] * k[c];
            vv[c] = q2[hpx][96 + h * 24 + c];
        }
        float rq = temp[h] / fmaxf(sqrtf(sqs), 1e-12f);
        float rk = 1.f / fmaxf(sqrtf(sks), 1e-12f);
        short qs[32], ks[32];
#pragma unroll
        for (int c = 0; c < 24; c++) { qs[c] = f2bf(q[c] * rq); ks[c] = f2bf(k[c] * rk); }
#pragma unroll
        for (int c = 24; c < 32; c++) { qs[c] = 0; ks[c] = 0; }
        size_t ro = ((size_t)bh * NPIX + n) * 32;
#pragma unroll
        for (int i = 0; i < 4; i++) {
            short8 a, bb;
#pragma unroll
            for (int j = 0; j < 8; j++) { a[j] = qs[i * 8 + j]; bb[j] = ks[i * 8 + j]; }
            *(short8*)(Qbf + ro + i * 8) = a;
            *(short8*)(Kbf + ro + i * 8) = bb;
        }
        int r5 = n & 31;
        int vcol = (n & ~31) + ((r5 & 15) * 2 + (r5 >> 4));
#pragma unroll
        for (int c = 0; c < 24; c++)
            Vbf[((size_t)bh * 32 + c) * NPIX + vcol] = f2bf(vv[c]);
#pragma unroll
        for (int c = 24; c < 32; c++)
            Vbf[((size_t)bh * 32 + c) * NPIX + vcol] = 0;
    }
}

// ============ K3: MFMA flash attention, LDS-staged K/V double buffer ===========
// grid: (qt=64, split=SPLIT, bh=4), block 256.
// Opart: [bh][SPLIT][32ch][4096] fp32; lpart: [bh][SPLIT][4096]
__global__ __launch_bounds__(256) void k_attn_mfma(const short* __restrict__ Qbf,
                                                   const short* __restrict__ Kbf,
                                                   const short* __restrict__ Vbf,
                                                   float* __restrict__ Opart,
                                                   float* __restrict__ lpart) {
    int qt = blockIdx.x, s = blockIdx.y, bh = blockIdx.z;
    int t = threadIdx.x;
    int w = t >> 6, lane = t & 63, l15 = lane & 15, quad = lane >> 4;

    __shared__ short tileK[2][32][40];
    __shared__ short tileV[2][32][40];
    __shared__ short P[4][16][40];

    int qrow0 = qt * 64 + w * 16;
    short8 aq = *(const short8*)(Qbf + ((size_t)bh * NPIX + qrow0 + l15) * 32 + quad * 8);

    int i = t & 127;
    int rr = i >> 2, qh = i & 3;
    bool isV = t >= 128;
    const short* srcK = Kbf + ((size_t)bh * NPIX + rr) * 32 + qh * 8;
    const short* srcV = Vbf + ((size_t)(bh * 32 + rr)) * NPIX + qh * 8;
    int dstoff = rr * 40 + qh * 8;

    int key0 = s * (NPIX / SPLIT);
    {
        short8 ld = isV ? *(const short8*)(srcV + key0)
                        : *(const short8*)(srcK + (size_t)key0 * 32);
        short* dst = (isV ? &tileV[0][0][0] : &tileK[0][0][0]) + dstoff;
        *(short8*)dst = ld;
    }

    floatx4 zf = {0.f, 0.f, 0.f, 0.f};
    floatx4 o0 = zf, o1 = zf;
    float ls[4] = {0.f, 0.f, 0.f, 0.f};

    const int NKT = (NPIX / SPLIT) / 32;
    for (int kt = 0; kt < NKT; kt++) {
        __syncthreads();
        int cur = kt & 1;
        short8 ld = {};
        if (kt < NKT - 1) {
            int kabs = key0 + (kt + 1) * 32;
            ld = isV ? *(const short8*)(srcV + kabs)
                     : *(const short8*)(srcK + (size_t)kabs * 32);
        }
        short8 b0  = *(const short8*)&tileK[cur][l15][quad * 8];
        short8 b1  = *(const short8*)&tileK[cur][l15 + 16][quad * 8];
        short8 vb0 = *(const short8*)&tileV[cur][l15][quad * 8];
        short8 vb1 = *(const short8*)&tileV[cur][l15 + 16][quad * 8];
        floatx4 s0 = __builtin_amdgcn_mfma_f32_16x16x32_bf16(aq, b0, zf, 0, 0, 0);
        floatx4 s1 = __builtin_amdgcn_mfma_f32_16x16x32_bf16(aq, b1, zf, 0, 0, 0);
#pragma unroll
        for (int r = 0; r < 4; r++) {
            float p0 = __expf(s0[r]);
            float p1 = __expf(s1[r]);
            ls[r] += p0 + p1;
            __hip_bfloat162 pk = __float22bfloat162_rn(make_float2(p0, p1));
            *(unsigned*)&P[w][quad * 4 + r][l15 * 2] = *(unsigned*)&pk;
        }
        short8 ap = *(const short8*)&P[w][l15][quad * 8];
        o0 = __builtin_amdgcn_mfma_f32_16x16x32_bf16(ap, vb0, o0, 0, 0, 0);
        o1 = __builtin_amdgcn_mfma_f32_16x16x32_bf16(ap, vb1, o1, 0, 0, 0);
        if (kt < NKT - 1) {
            short* dst = (isV ? &tileV[1 - cur][0][0] : &tileK[1 - cur][0][0]) + dstoff;
            *(short8*)dst = ld;
        }
    }
#pragma unroll
    for (int m = 1; m < 16; m <<= 1) {
#pragma unroll
        for (int r = 0; r < 4; r++) ls[r] += __shfl_xor(ls[r], m, 64);
    }
#pragma unroll
    for (int r = 0; r < 4; r++) {
        int n = qrow0 + quad * 4 + r;
        size_t base2 = (size_t)(bh * SPLIT + s) * 32;
        Opart[(base2 + l15) * NPIX + n] = o0[r];
        Opart[(base2 + 16 + l15) * NPIX + n] = o1[r];
        if (l15 == 0) lpart[((size_t)(bh * SPLIT + s)) * NPIX + n] = ls[r];
    }
}

// ============ K4: reduce splits + normalize + proj (MFMA) + residual ===========
// grid (128, NB), block 256. Block handles 32 px.
__global__ __launch_bounds__(256) void k_projred(
    const float* __restrict__ x, const float* __restrict__ Opart,
    const float* __restrict__ lpart, const short* __restrict__ projwbf,
    const float* __restrict__ bias, float* __restrict__ x1)
{
    int px0 = blockIdx.x * 32;
    int b = blockIdx.y;
    int t = threadIdx.x;
    int w = t >> 6, lane = t & 63, l15 = lane & 15, quad = lane >> 4;

    __shared__ __align__(16) short Ash[32][72];
    __shared__ float rlsh[2][32];

    if (t < 64) {
        int h = t >> 5, px = t & 31;
        float l = 0.f;
#pragma unroll
        for (int s = 0; s < SPLIT; s++)
            l += lpart[((size_t)((b * 2 + h) * SPLIT + s)) * NPIX + px0 + px];
        rlsh[h][px] = 1.f / l;
    }
    {
        int px = t & 31, j = t >> 5;
        *(unsigned*)&Ash[px][48 + j * 2] = 0u;
    }
    __syncthreads();
#pragma unroll
    for (int pi = 0; pi < 6; pi++) {
        int idx = pi * 256 + t;
        int px = idx & 31, c = idx >> 5;
        int h = c / 24, ch = c % 24;
        float acc = 0.f;
#pragma unroll
        for (int s = 0; s < SPLIT; s++)
            acc += Opart[(((size_t)((b * 2 + h) * SPLIT + s)) * 32 + ch) * NPIX + px0 + px];
        Ash[px][c] = f2bf(acc * rlsh[h][px]);
    }
    __syncthreads();
    floatx4 zf = {0.f, 0.f, 0.f, 0.f};
    for (int job = w; job < 6; job += 4) {
        int pt = job / 3, ot = job % 3;
        short8 a0 = *(const short8*)&Ash[pt * 16 + l15][quad * 8];
        short8 a1 = *(const short8*)&Ash[pt * 16 + l15][32 + quad * 8];
        const short* wb = projwbf + (ot * 16 + l15) * 64;
        short8 b0 = *(const short8*)(wb + quad * 8);
        short8 b1 = *(const short8*)(wb + 32 + quad * 8);
        floatx4 c = __builtin_amdgcn_mfma_f32_16x16x32_bf16(a0, b0, zf, 0, 0, 0);
        c = __builtin_amdgcn_mfma_f32_16x16x32_bf16(a1, b1, c, 0, 0, 0);
        int oc = ot * 16 + l15;
        float bi = bias[oc];
#pragma unroll
        for (int r = 0; r < 4; r++) {
            int n = px0 + pt * 16 + quad * 4 + r;
            size_t idx = ((size_t)b * 48 + oc) * NPIX + n;
            x1[idx] = x[idx] + c[r] + bi;
        }
    }
}

// ============ K6: dw3 on fp_pre + GELU-gate + fo 1x1 (MFMA) + residual =========
// grid (4, 64, NB), block 256. 16 px per block.
__global__ __launch_bounds__(256) void k_dwgatefo(
    const short* __restrict__ fp_pre, const float* __restrict__ fdww,
    const float* __restrict__ fdwb, const short* __restrict__ fowbf,
    const float* __restrict__ fob, const float* __restrict__ x1,
    float* __restrict__ out)
{
    int px0 = blockIdx.x * 16;
    int y = blockIdx.y, b = blockIdx.z;
    int t = threadIdx.x;
    int w = t >> 6, lane = t & 63, l15 = lane & 15, quad = lane >> 4;

    __shared__ short yv[16][104];

    int px = t & 15, g = t >> 4;   // 16 groups x 6 gate-pairs
    int gx = px0 + px;
    const short* base = fp_pre + (size_t)b * 192 * NPIX;
    for (int i = 0; i < 6; i++) {
        int c = g * 6 + i;
        float a  = dw3_at(base + (size_t)c * NPIX, fdww + c * 9, gx, y, fdwb[c]);
        int c2 = c + 96;
        float g2 = dw3_at(base + (size_t)c2 * NPIX, fdww + c2 * 9, gx, y, fdwb[c2]);
        float ge = 0.5f * a * (1.f + erff(a * 0.70710678118654752f));
        yv[px][c] = f2bf(ge * g2);
    }
    __syncthreads();
    if (w < 3) {
        floatx4 c = {0.f, 0.f, 0.f, 0.f};
#pragma unroll
        for (int k = 0; k < 3; k++) {
            short8 a = *(const short8*)&yv[l15][k * 32 + quad * 8];
            short8 bb = *(const short8*)(fowbf + (w * 16 + l15) * 96 + k * 32 + quad * 8);
            c = __builtin_amdgcn_mfma_f32_16x16x32_bf16(a, bb, c, 0, 0, 0);
        }
        int oc = w * 16 + l15;
        float bi = fob[oc];
#pragma unroll
        for (int r = 0; r < 4; r++) {
            int n = y * 64 + px0 + quad * 4 + r;
            size_t idx = ((size_t)b * 48 + oc) * NPIX + n;
            out[idx] = x1[idx] + c[r] + bi;
        }
    }
}

extern "C" void kernel_launch(void* const* d_in, const int* in_sizes, int n_in,
                              void* d_out, int out_size, void* d_ws, size_t ws_size,
                              hipStream_t stream) {
    const float* x       = (const float*)d_in[0];
    const float* n1w     = (const float*)d_in[1];
    const float* n1b     = (const float*)d_in[2];
    const float* qkv_w   = (const float*)d_in[3];
    const float* qkv_b   = (const float*)d_in[4];
    const float* qkvdw_w = (const float*)d_in[5];
    const float* qkvdw_b = (const float*)d_in[6];
    const float* temp    = (const float*)d_in[7];
    const float* proj_w  = (const float*)d_in[8];
    const float* proj_b  = (const float*)d_in[9];
    const float* n2w     = (const float*)d_in[10];
    const float* n2b     = (const float*)d_in[11];
    const float* fi_w    = (const float*)d_in[12];
    const float* fi_b    = (const float*)d_in[13];
    const float* fdw_w   = (const float*)d_in[14];
    const float* fdw_b   = (const float*)d_in[15];
    const float* fo_w    = (const float*)d_in[16];
    const float* fo_b    = (const float*)d_in[17];

    float* ws = (float*)d_ws;
    short* qkv_pre = (short*)ws;                       // 1,179,648 sh = 589,824 f
    short* fp_pre  = (short*)(ws + 589824);            // 1,572,864 sh = 786,432 f
    short* Qbf     = (short*)(ws + 1376256);           // 524,288 sh
    short* Kbf     = (short*)(ws + 1638400);           // 524,288 sh
    short* Vbf     = (short*)(ws + 1900544);           // 524,288 sh
    float* Opart   = ws + 2162688;                     // 4*SPLIT*32*4096 = 2,097,152 f
    float* lpart   = ws + 4259840;                     // 65,536 f
    float* x1      = ws + 4325376;                     // 393,216 f
    short* qkvwbf  = (short*)(ws + 4718592);           // 9216 sh
    short* fiwbf   = qkvwbf + 9216;                    // 12288 sh
    short* fowbf   = fiwbf + 12288;                    // 4608 sh
    short* projwbf = fowbf + 4608;                     // 3072 sh

    {   // weights -> bf16 B-layout
        int total = 144 * 64 + 192 * 64 + 48 * 96 + 48 * 64;
        k_prepw<<<(total + 255) / 256, 256, 0, stream>>>(qkv_w, fi_w, fo_w, proj_w,
                                                         qkvwbf, fiwbf, fowbf, projwbf);
    }
    {   // LN1 + qkv 1x1 (MFMA) -> qkv_pre bf16
        dim3 g(128, NB);
        k_ln_conv_mfma<<<g, 256, 0, stream>>>(x, n1w, n1b, qkvwbf, qkv_b, qkv_pre, 144);
    }
    {   // dw3 + heads pack
        dim3 g(4, 64, NB);
        k_dw3heads<<<g, 256, 0, stream>>>(qkv_pre, qkvdw_w, qkvdw_b, temp, Qbf, Kbf, Vbf);
    }
    {   // attention
        dim3 g(64, SPLIT, 4);
        k_attn_mfma<<<g, 256, 0, stream>>>(Qbf, Kbf, Vbf, Opart, lpart);
    }
    {   // reduce + proj(MFMA) + residual
        dim3 g(128, NB);
        k_projred<<<g, 256, 0, stream>>>(x, Opart, lpart, projwbf, proj_b, x1);
    }
    {   // LN2 + fi 1x1 (MFMA) -> fp_pre bf16
        dim3 g(128, NB);
        k_ln_conv_mfma<<<g, 256, 0, stream>>>(x1, n2w, n2b, fiwbf, fi_b, fp_pre, 192);
    }
    {   // dw3 + gate + fo(MFMA) + residual
        dim3 g(4, 64, NB);
        k_dwgatefo<<<g, 256, 0, stream>>>(fp_pre, fdw_w, fdw_b, fowbf, fo_b, x1,
                                          (float*)d_out);
    }
}

// Round 8
// 151.923 us; speedup vs baseline: 1.1051x; 1.1051x over previous
//
#include <hip/hip_runtime.h>
#include <hip/hip_bf16.h>
#include <math.h>

#define NPIX 4096   // 64*64
#define DIMC 48
#define NB 2
#define SPLIT 4

typedef __attribute__((ext_vector_type(8))) short short8;
typedef __attribute__((ext_vector_type(4))) short short4s;
typedef __attribute__((ext_vector_type(4))) float floatx4;

static __device__ inline short f2bf(float f) {
    union { float f; unsigned u; } v; v.f = f;
    unsigned r = (v.u + 0x7FFFu + ((v.u >> 16) & 1u)) >> 16;
    return (short)r;
}
static __device__ inline float bf2f(short s) {
    union { unsigned u; float f; } v;
    v.u = ((unsigned)(unsigned short)s) << 16;
    return v.f;
}

// ============ K0: prep bf16 B-layout weights (rows padded to 64 k, zeros) ======
__global__ void k_prepw(const float* __restrict__ qkvw, const float* __restrict__ fiw,
                        const float* __restrict__ fow, const float* __restrict__ projw,
                        short* __restrict__ qkvwbf, short* __restrict__ fiwbf,
                        short* __restrict__ fowbf, short* __restrict__ projwbf) {
    int idx = blockIdx.x * 256 + threadIdx.x;
    if (idx < 144 * 64) {
        int o = idx >> 6, c = idx & 63;
        qkvwbf[idx] = (c < 48) ? f2bf(qkvw[o * 48 + c]) : (short)0;
        return;
    }
    idx -= 144 * 64;
    if (idx < 192 * 64) {
        int o = idx >> 6, c = idx & 63;
        fiwbf[idx] = (c < 48) ? f2bf(fiw[o * 48 + c]) : (short)0;
        return;
    }
    idx -= 192 * 64;
    if (idx < 48 * 96) {
        fowbf[idx] = f2bf(fow[idx]);
        return;
    }
    idx -= 48 * 96;
    if (idx < 48 * 64) {
        int o = idx >> 6, c = idx & 63;
        projwbf[idx] = (c < 48) ? f2bf(projw[o * 48 + c]) : (short)0;
    }
}

// ============ K1/K5: LayerNorm + 1x1 conv (MFMA), no halo ======================
// grid (128, NB), block 256. 32 px per block. out: bf16 [b][OC][4096].
__global__ __launch_bounds__(256) void k_ln_conv_mfma(
    const float* __restrict__ xin, const float* __restrict__ lw, const float* __restrict__ lb,
    const short* __restrict__ wbf, const float* __restrict__ cb,
    short* __restrict__ outbf, int OC)
{
    int px0 = blockIdx.x * 32;
    int b = blockIdx.y;
    int t = threadIdx.x;
    int w = t >> 6, lane = t & 63, l15 = lane & 15, quad = lane >> 4;

    __shared__ float psum[8][32], psq[8][32];
    __shared__ float muS[32], rsS[32];
    __shared__ short xnbf[32][72];

    int px = t & 31, g = t >> 5;     // 8 groups x 6 channels
    *(unsigned*)&xnbf[px][48 + g * 2] = 0u;

    float v[6];
    float s = 0.f, sq = 0.f;
#pragma unroll
    for (int i = 0; i < 6; i++) {
        v[i] = xin[((size_t)b * 48 + g * 6 + i) * (size_t)NPIX + px0 + px];
        s += v[i]; sq += v[i] * v[i];
    }
    psum[g][px] = s; psq[g][px] = sq;
    __syncthreads();
    if (t < 32) {
        float ss = 0.f, qq = 0.f;
#pragma unroll
        for (int i = 0; i < 8; i++) { ss += psum[i][t]; qq += psq[i][t]; }
        float mu = ss * (1.f / 48.f);
        float var = qq * (1.f / 48.f) - mu * mu;
        muS[t] = mu; rsS[t] = rsqrtf(var + 1e-5f);
    }
    __syncthreads();
    {
        float mu = muS[px], rs = rsS[px];
#pragma unroll
        for (int i = 0; i < 6; i++) {
            int c = g * 6 + i;
            xnbf[px][c] = f2bf((v[i] - mu) * rs * lw[c] + lb[c]);
        }
    }
    __syncthreads();
    floatx4 zf = {0.f, 0.f, 0.f, 0.f};
    int oct = OC >> 4;
    int njobs = 2 * oct;
    for (int job = w; job < njobs; job += 4) {
        int pt = job / oct, ot = job % oct;
        short8 a0 = *(const short8*)&xnbf[pt * 16 + l15][quad * 8];
        short8 a1 = *(const short8*)&xnbf[pt * 16 + l15][32 + quad * 8];
        const short* wb = wbf + (ot * 16 + l15) * 64;
        short8 b0 = *(const short8*)(wb + quad * 8);
        short8 b1 = *(const short8*)(wb + 32 + quad * 8);
        floatx4 c = __builtin_amdgcn_mfma_f32_16x16x32_bf16(a0, b0, zf, 0, 0, 0);
        c = __builtin_amdgcn_mfma_f32_16x16x32_bf16(a1, b1, c, 0, 0, 0);
        int oc = ot * 16 + l15;
        float bi = cb[oc];
        short4s st;
#pragma unroll
        for (int r = 0; r < 4; r++) st[r] = f2bf(c[r] + bi);
        *(short4s*)(outbf + ((size_t)b * OC + oc) * (size_t)NPIX + px0 + pt * 16 + quad * 4) = st;
    }
}

// ============ K2: dw3 (LDS-staged) + l2norm/temp + bf16 MFMA pack ==============
// grid (4, 64, NB), block 256. 16 px (one row segment) per block.
// Staged window: 3 rows x 144 ch x 32 px (aligned), short8 coalesced loads.
__global__ __launch_bounds__(256) void k_dw3heads(
    const short* __restrict__ qkv_pre, const float* __restrict__ dww,
    const float* __restrict__ dwb, const float* __restrict__ temp,
    short* __restrict__ Qbf, short* __restrict__ Kbf, short* __restrict__ Vbf)
{
    int px0 = blockIdx.x * 16;
    int y = blockIdx.y, b = blockIdx.z;
    int t = threadIdx.x;
    int wx0 = px0 - 8; if (wx0 < 0) wx0 = 0; if (wx0 > 32) wx0 = 32;
    int xoff = px0 - wx0;

    __shared__ short stage[3][144][40];   // 80B rows: 16B-aligned, conflict-free
    __shared__ float q2[16][148];

    // cooperative staging: 3*144 row-segments of 32 px, as 4x short8 each
    for (int seg = t; seg < 3 * 144 * 4; seg += 256) {
        int q = seg & 3, idx = seg >> 2;
        int c = idx % 144, r = idx / 144;
        int yy = y + r - 1;
        short8 ld = {};
        if ((unsigned)yy < 64u)
            ld = *(const short8*)(qkv_pre + (size_t)(b * 144 + c) * NPIX + yy * 64 + wx0 + q * 8);
        *(short8*)&stage[r][c][q * 8] = ld;
    }
    __syncthreads();
    int px = t & 15, g = t >> 4;   // 16 groups x 9 channels
    {
        int sbase = xoff + px;
        for (int i = 0; i < 9; i++) {
            int c = g * 9 + i;
            const float* wp = dww + c * 9;
            float acc = dwb[c];
#pragma unroll
            for (int dy = 0; dy < 3; dy++) {
#pragma unroll
                for (int dx = -1; dx <= 1; dx++) {
                    int si = sbase + dx;
                    if ((unsigned)si < 32u)
                        acc += bf2f(stage[dy][c][si]) * wp[dy * 3 + dx + 1];
                }
            }
            q2[px][c] = acc;
        }
    }
    __syncthreads();
    if (t < 32) {
        int hpx = t & 15, h = t >> 4;
        int n = y * 64 + px0 + hpx;
        int bh = b * 2 + h;
        float q[24], k[24], vv[24]; float sqs = 0.f, sks = 0.f;
#pragma unroll
        for (int c = 0; c < 24; c++) {
            q[c] = q2[hpx][h * 24 + c];       sqs += q[c] * q[c];
            k[c] = q2[hpx][48 + h * 24 + c];  sks += k[c] * k[c];
            vv[c] = q2[hpx][96 + h * 24 + c];
        }
        float rq = temp[h] / fmaxf(sqrtf(sqs), 1e-12f);
        float rk = 1.f / fmaxf(sqrtf(sks), 1e-12f);
        short qs[32], ks[32];
#pragma unroll
        for (int c = 0; c < 24; c++) { qs[c] = f2bf(q[c] * rq); ks[c] = f2bf(k[c] * rk); }
#pragma unroll
        for (int c = 24; c < 32; c++) { qs[c] = 0; ks[c] = 0; }
        size_t ro = ((size_t)bh * NPIX + n) * 32;
#pragma unroll
        for (int i = 0; i < 4; i++) {
            short8 a, bb;
#pragma unroll
            for (int j = 0; j < 8; j++) { a[j] = qs[i * 8 + j]; bb[j] = ks[i * 8 + j]; }
            *(short8*)(Qbf + ro + i * 8) = a;
            *(short8*)(Kbf + ro + i * 8) = bb;
        }
        int r5 = n & 31;
        int vcol = (n & ~31) + ((r5 & 15) * 2 + (r5 >> 4));
#pragma unroll
        for (int c = 0; c < 24; c++)
            Vbf[((size_t)bh * 32 + c) * NPIX + vcol] = f2bf(vv[c]);
#pragma unroll
        for (int c = 24; c < 32; c++)
            Vbf[((size_t)bh * 32 + c) * NPIX + vcol] = 0;
    }
}

// ============ K3: MFMA flash attention, LDS-staged K/V double buffer ===========
// grid: (qt=64, split=SPLIT, bh=4), block 256.
// Opart: [bh][SPLIT][32ch][4096] fp32; lpart: [bh][SPLIT][4096]
__global__ __launch_bounds__(256) void k_attn_mfma(const short* __restrict__ Qbf,
                                                   const short* __restrict__ Kbf,
                                                   const short* __restrict__ Vbf,
                                                   float* __restrict__ Opart,
                                                   float* __restrict__ lpart) {
    int qt = blockIdx.x, s = blockIdx.y, bh = blockIdx.z;
    int t = threadIdx.x;
    int w = t >> 6, lane = t & 63, l15 = lane & 15, quad = lane >> 4;

    __shared__ short tileK[2][32][40];
    __shared__ short tileV[2][32][40];
    __shared__ short P[4][16][40];

    int qrow0 = qt * 64 + w * 16;
    short8 aq = *(const short8*)(Qbf + ((size_t)bh * NPIX + qrow0 + l15) * 32 + quad * 8);

    int i = t & 127;
    int rr = i >> 2, qh = i & 3;
    bool isV = t >= 128;
    const short* srcK = Kbf + ((size_t)bh * NPIX + rr) * 32 + qh * 8;
    const short* srcV = Vbf + ((size_t)(bh * 32 + rr)) * NPIX + qh * 8;
    int dstoff = rr * 40 + qh * 8;

    int key0 = s * (NPIX / SPLIT);
    {
        short8 ld = isV ? *(const short8*)(srcV + key0)
                        : *(const short8*)(srcK + (size_t)key0 * 32);
        short* dst = (isV ? &tileV[0][0][0] : &tileK[0][0][0]) + dstoff;
        *(short8*)dst = ld;
    }

    floatx4 zf = {0.f, 0.f, 0.f, 0.f};
    floatx4 o0 = zf, o1 = zf;
    float ls[4] = {0.f, 0.f, 0.f, 0.f};

    const int NKT = (NPIX / SPLIT) / 32;
    for (int kt = 0; kt < NKT; kt++) {
        __syncthreads();
        int cur = kt & 1;
        short8 ld = {};
        if (kt < NKT - 1) {
            int kabs = key0 + (kt + 1) * 32;
            ld = isV ? *(const short8*)(srcV + kabs)
                     : *(const short8*)(srcK + (size_t)kabs * 32);
        }
        short8 b0  = *(const short8*)&tileK[cur][l15][quad * 8];
        short8 b1  = *(const short8*)&tileK[cur][l15 + 16][quad * 8];
        short8 vb0 = *(const short8*)&tileV[cur][l15][quad * 8];
        short8 vb1 = *(const short8*)&tileV[cur][l15 + 16][quad * 8];
        floatx4 s0 = __builtin_amdgcn_mfma_f32_16x16x32_bf16(aq, b0, zf, 0, 0, 0);
        floatx4 s1 = __builtin_amdgcn_mfma_f32_16x16x32_bf16(aq, b1, zf, 0, 0, 0);
#pragma unroll
        for (int r = 0; r < 4; r++) {
            float p0 = __expf(s0[r]);
            float p1 = __expf(s1[r]);
            ls[r] += p0 + p1;
            __hip_bfloat162 pk = __float22bfloat162_rn(make_float2(p0, p1));
            *(unsigned*)&P[w][quad * 4 + r][l15 * 2] = *(unsigned*)&pk;
        }
        short8 ap = *(const short8*)&P[w][l15][quad * 8];
        o0 = __builtin_amdgcn_mfma_f32_16x16x32_bf16(ap, vb0, o0, 0, 0, 0);
        o1 = __builtin_amdgcn_mfma_f32_16x16x32_bf16(ap, vb1, o1, 0, 0, 0);
        if (kt < NKT - 1) {
            short* dst = (isV ? &tileV[1 - cur][0][0] : &tileK[1 - cur][0][0]) + dstoff;
            *(short8*)dst = ld;
        }
    }
#pragma unroll
    for (int m = 1; m < 16; m <<= 1) {
#pragma unroll
        for (int r = 0; r < 4; r++) ls[r] += __shfl_xor(ls[r], m, 64);
    }
#pragma unroll
    for (int r = 0; r < 4; r++) {
        int n = qrow0 + quad * 4 + r;
        size_t base2 = (size_t)(bh * SPLIT + s) * 32;
        Opart[(base2 + l15) * NPIX + n] = o0[r];
        Opart[(base2 + 16 + l15) * NPIX + n] = o1[r];
        if (l15 == 0) lpart[((size_t)(bh * SPLIT + s)) * NPIX + n] = ls[r];
    }
}

// ============ K4: reduce splits + normalize + proj (MFMA) + residual ===========
// grid (128, NB), block 256. Block handles 32 px.
__global__ __launch_bounds__(256) void k_projred(
    const float* __restrict__ x, const float* __restrict__ Opart,
    const float* __restrict__ lpart, const short* __restrict__ projwbf,
    const float* __restrict__ bias, float* __restrict__ x1)
{
    int px0 = blockIdx.x * 32;
    int b = blockIdx.y;
    int t = threadIdx.x;
    int w = t >> 6, lane = t & 63, l15 = lane & 15, quad = lane >> 4;

    __shared__ __align__(16) short Ash[32][72];
    __shared__ float rlsh[2][32];

    if (t < 64) {
        int h = t >> 5, px = t & 31;
        float l = 0.f;
#pragma unroll
        for (int s = 0; s < SPLIT; s++)
            l += lpart[((size_t)((b * 2 + h) * SPLIT + s)) * NPIX + px0 + px];
        rlsh[h][px] = 1.f / l;
    }
    {
        int px = t & 31, j = t >> 5;
        *(unsigned*)&Ash[px][48 + j * 2] = 0u;
    }
    __syncthreads();
#pragma unroll
    for (int pi = 0; pi < 6; pi++) {
        int idx = pi * 256 + t;
        int px = idx & 31, c = idx >> 5;
        int h = c / 24, ch = c % 24;
        float acc = 0.f;
#pragma unroll
        for (int s = 0; s < SPLIT; s++)
            acc += Opart[(((size_t)((b * 2 + h) * SPLIT + s)) * 32 + ch) * NPIX + px0 + px];
        Ash[px][c] = f2bf(acc * rlsh[h][px]);
    }
    __syncthreads();
    floatx4 zf = {0.f, 0.f, 0.f, 0.f};
    for (int job = w; job < 6; job += 4) {
        int pt = job / 3, ot = job % 3;
        short8 a0 = *(const short8*)&Ash[pt * 16 + l15][quad * 8];
        short8 a1 = *(const short8*)&Ash[pt * 16 + l15][32 + quad * 8];
        const short* wb = projwbf + (ot * 16 + l15) * 64;
        short8 b0 = *(const short8*)(wb + quad * 8);
        short8 b1 = *(const short8*)(wb + 32 + quad * 8);
        floatx4 c = __builtin_amdgcn_mfma_f32_16x16x32_bf16(a0, b0, zf, 0, 0, 0);
        c = __builtin_amdgcn_mfma_f32_16x16x32_bf16(a1, b1, c, 0, 0, 0);
        int oc = ot * 16 + l15;
        float bi = bias[oc];
#pragma unroll
        for (int r = 0; r < 4; r++) {
            int n = px0 + pt * 16 + quad * 4 + r;
            size_t idx = ((size_t)b * 48 + oc) * NPIX + n;
            x1[idx] = x[idx] + c[r] + bi;
        }
    }
}

// ============ K6: dw3 (LDS-staged) + GELU-gate + fo 1x1 (MFMA) + residual ======
// grid (4, 64, NB), block 256. 16 px per block.
__global__ __launch_bounds__(256) void k_dwgatefo(
    const short* __restrict__ fp_pre, const float* __restrict__ fdww,
    const float* __restrict__ fdwb, const short* __restrict__ fowbf,
    const float* __restrict__ fob, const float* __restrict__ x1,
    float* __restrict__ out)
{
    int px0 = blockIdx.x * 16;
    int y = blockIdx.y, b = blockIdx.z;
    int t = threadIdx.x;
    int w = t >> 6, lane = t & 63, l15 = lane & 15, quad = lane >> 4;
    int wx0 = px0 - 8; if (wx0 < 0) wx0 = 0; if (wx0 > 32) wx0 = 32;
    int xoff = px0 - wx0;

    __shared__ short stage[3][192][40];   // 46 KB
    __shared__ short yv[16][104];

    for (int seg = t; seg < 3 * 192 * 4; seg += 256) {
        int q = seg & 3, idx = seg >> 2;
        int c = idx % 192, r = idx / 192;
        int yy = y + r - 1;
        short8 ld = {};
        if ((unsigned)yy < 64u)
            ld = *(const short8*)(fp_pre + (size_t)(b * 192 + c) * NPIX + yy * 64 + wx0 + q * 8);
        *(short8*)&stage[r][c][q * 8] = ld;
    }
    __syncthreads();
    int px = t & 15, g = t >> 4;   // 16 groups x 6 gate-pairs
    {
        int sbase = xoff + px;
        for (int i = 0; i < 6; i++) {
            int c = g * 6 + i;
            const float* wp  = fdww + c * 9;
            const float* wp2 = fdww + (c + 96) * 9;
            float a  = fdwb[c];
            float g2 = fdwb[c + 96];
#pragma unroll
            for (int dy = 0; dy < 3; dy++) {
#pragma unroll
                for (int dx = -1; dx <= 1; dx++) {
                    int si = sbase + dx;
                    if ((unsigned)si < 32u) {
                        a  += bf2f(stage[dy][c][si])      * wp[dy * 3 + dx + 1];
                        g2 += bf2f(stage[dy][c + 96][si]) * wp2[dy * 3 + dx + 1];
                    }
                }
            }
            float ge = 0.5f * a * (1.f + erff(a * 0.70710678118654752f));
            yv[px][c] = f2bf(ge * g2);
        }
    }
    __syncthreads();
    if (w < 3) {
        floatx4 c = {0.f, 0.f, 0.f, 0.f};
#pragma unroll
        for (int k = 0; k < 3; k++) {
            short8 a = *(const short8*)&yv[l15][k * 32 + quad * 8];
            short8 bb = *(const short8*)(fowbf + (w * 16 + l15) * 96 + k * 32 + quad * 8);
            c = __builtin_amdgcn_mfma_f32_16x16x32_bf16(a, bb, c, 0, 0, 0);
        }
        int oc = w * 16 + l15;
        float bi = fob[oc];
#pragma unroll
        for (int r = 0; r < 4; r++) {
            int n = y * 64 + px0 + quad * 4 + r;
            size_t idx = ((size_t)b * 48 + oc) * NPIX + n;
            out[idx] = x1[idx] + c[r] + bi;
        }
    }
}

extern "C" void kernel_launch(void* const* d_in, const int* in_sizes, int n_in,
                              void* d_out, int out_size, void* d_ws, size_t ws_size,
                              hipStream_t stream) {
    const float* x       = (const float*)d_in[0];
    const float* n1w     = (const float*)d_in[1];
    const float* n1b     = (const float*)d_in[2];
    const float* qkv_w   = (const float*)d_in[3];
    const float* qkv_b   = (const float*)d_in[4];
    const float* qkvdw_w = (const float*)d_in[5];
    const float* qkvdw_b = (const float*)d_in[6];
    const float* temp    = (const float*)d_in[7];
    const float* proj_w  = (const float*)d_in[8];
    const float* proj_b  = (const float*)d_in[9];
    const float* n2w     = (const float*)d_in[10];
    const float* n2b     = (const float*)d_in[11];
    const float* fi_w    = (const float*)d_in[12];
    const float* fi_b    = (const float*)d_in[13];
    const float* fdw_w   = (const float*)d_in[14];
    const float* fdw_b   = (const float*)d_in[15];
    const float* fo_w    = (const float*)d_in[16];
    const float* fo_b    = (const float*)d_in[17];

    float* ws = (float*)d_ws;
    short* qkv_pre = (short*)ws;                       // 1,179,648 sh = 589,824 f
    short* fp_pre  = (short*)(ws + 589824);            // 1,572,864 sh = 786,432 f
    short* Qbf     = (short*)(ws + 1376256);           // 524,288 sh
    short* Kbf     = (short*)(ws + 1638400);           // 524,288 sh
    short* Vbf     = (short*)(ws + 1900544);           // 524,288 sh
    float* Opart   = ws + 2162688;                     // 4*SPLIT*32*4096 = 2,097,152 f
    float* lpart   = ws + 4259840;                     // 65,536 f
    float* x1      = ws + 4325376;                     // 393,216 f
    short* qkvwbf  = (short*)(ws + 4718592);           // 9216 sh
    short* fiwbf   = qkvwbf + 9216;                    // 12288 sh
    short* fowbf   = fiwbf + 12288;                    // 4608 sh
    short* projwbf = fowbf + 4608;                     // 3072 sh

    {   // weights -> bf16 B-layout
        int total = 144 * 64 + 192 * 64 + 48 * 96 + 48 * 64;
        k_prepw<<<(total + 255) / 256, 256, 0, stream>>>(qkv_w, fi_w, fo_w, proj_w,
                                                         qkvwbf, fiwbf, fowbf, projwbf);
    }
    {   // LN1 + qkv 1x1 (MFMA) -> qkv_pre bf16
        dim3 g(128, NB);
        k_ln_conv_mfma<<<g, 256, 0, stream>>>(x, n1w, n1b, qkvwbf, qkv_b, qkv_pre, 144);
    }
    {   // dw3 (LDS-staged) + heads pack
        dim3 g(4, 64, NB);
        k_dw3heads<<<g, 256, 0, stream>>>(qkv_pre, qkvdw_w, qkvdw_b, temp, Qbf, Kbf, Vbf);
    }
    {   // attention
        dim3 g(64, SPLIT, 4);
        k_attn_mfma<<<g, 256, 0, stream>>>(Qbf, Kbf, Vbf, Opart, lpart);
    }
    {   // reduce + proj(MFMA) + residual
        dim3 g(128, NB);
        k_projred<<<g, 256, 0, stream>>>(x, Opart, lpart, projwbf, proj_b, x1);
    }
    {   // LN2 + fi 1x1 (MFMA) -> fp_pre bf16
        dim3 g(128, NB);
        k_ln_conv_mfma<<<g, 256, 0, stream>>>(x1, n2w, n2b, fiwbf, fi_b, fp_pre, 192);
    }
    {   // dw3 (LDS-staged) + gate + fo(MFMA) + residual
        dim3 g(4, 64, NB);
        k_dwgatefo<<<g, 256, 0, stream>>>(fp_pre, fdw_w, fdw_b, fowbf, fo_b, x1,
                                          (float*)d_out);
    }
}

// Round 9
// 150.343 us; speedup vs baseline: 1.1167x; 1.0105x over previous
//
#include <hip/hip_runtime.h>
#include <hip/hip_bf16.h>
#include <math.h>

#define NPIX 4096   // 64*64
#define DIMC 48
#define NB 2
#define SPLIT 4

typedef __attribute__((ext_vector_type(8))) short short8;
typedef __attribute__((ext_vector_type(4))) short short4s;
typedef __attribute__((ext_vector_type(4))) float floatx4;

static __device__ inline short f2bf(float f) {
    union { float f; unsigned u; } v; v.f = f;
    unsigned r = (v.u + 0x7FFFu + ((v.u >> 16) & 1u)) >> 16;
    return (short)r;
}
static __device__ inline float bf2f(short s) {
    union { unsigned u; float f; } v;
    v.u = ((unsigned)(unsigned short)s) << 16;
    return v.f;
}

// ============ K0: prep bf16 B-layout weights (rows padded to 64 k, zeros) ======
__global__ void k_prepw(const float* __restrict__ qkvw, const float* __restrict__ fiw,
                        const float* __restrict__ fow, const float* __restrict__ projw,
                        short* __restrict__ qkvwbf, short* __restrict__ fiwbf,
                        short* __restrict__ fowbf, short* __restrict__ projwbf) {
    int idx = blockIdx.x * 256 + threadIdx.x;
    if (idx < 144 * 64) {
        int o = idx >> 6, c = idx & 63;
        qkvwbf[idx] = (c < 48) ? f2bf(qkvw[o * 48 + c]) : (short)0;
        return;
    }
    idx -= 144 * 64;
    if (idx < 192 * 64) {
        int o = idx >> 6, c = idx & 63;
        fiwbf[idx] = (c < 48) ? f2bf(fiw[o * 48 + c]) : (short)0;
        return;
    }
    idx -= 192 * 64;
    if (idx < 48 * 96) {
        fowbf[idx] = f2bf(fow[idx]);
        return;
    }
    idx -= 48 * 96;
    if (idx < 48 * 64) {
        int o = idx >> 6, c = idx & 63;
        projwbf[idx] = (c < 48) ? f2bf(projw[o * 48 + c]) : (short)0;
    }
}

// ============ K1: LayerNorm + 1x1 conv (MFMA), no halo =========================
// grid (128, NB), block 256. 32 px per block. out: bf16 [b][OC][4096].
__global__ __launch_bounds__(256) void k_ln_conv_mfma(
    const float* __restrict__ xin, const float* __restrict__ lw, const float* __restrict__ lb,
    const short* __restrict__ wbf, const float* __restrict__ cb,
    short* __restrict__ outbf, int OC)
{
    int px0 = blockIdx.x * 32;
    int b = blockIdx.y;
    int t = threadIdx.x;
    int w = t >> 6, lane = t & 63, l15 = lane & 15, quad = lane >> 4;

    __shared__ float psum[8][32], psq[8][32];
    __shared__ float muS[32], rsS[32];
    __shared__ short xnbf[32][72];

    int px = t & 31, g = t >> 5;     // 8 groups x 6 channels
    *(unsigned*)&xnbf[px][48 + g * 2] = 0u;

    float v[6];
    float s = 0.f, sq = 0.f;
#pragma unroll
    for (int i = 0; i < 6; i++) {
        v[i] = xin[((size_t)b * 48 + g * 6 + i) * (size_t)NPIX + px0 + px];
        s += v[i]; sq += v[i] * v[i];
    }
    psum[g][px] = s; psq[g][px] = sq;
    __syncthreads();
    if (t < 32) {
        float ss = 0.f, qq = 0.f;
#pragma unroll
        for (int i = 0; i < 8; i++) { ss += psum[i][t]; qq += psq[i][t]; }
        float mu = ss * (1.f / 48.f);
        float var = qq * (1.f / 48.f) - mu * mu;
        muS[t] = mu; rsS[t] = rsqrtf(var + 1e-5f);
    }
    __syncthreads();
    {
        float mu = muS[px], rs = rsS[px];
#pragma unroll
        for (int i = 0; i < 6; i++) {
            int c = g * 6 + i;
            xnbf[px][c] = f2bf((v[i] - mu) * rs * lw[c] + lb[c]);
        }
    }
    __syncthreads();
    floatx4 zf = {0.f, 0.f, 0.f, 0.f};
    int oct = OC >> 4;
    int njobs = 2 * oct;
    for (int job = w; job < njobs; job += 4) {
        int pt = job / oct, ot = job % oct;
        short8 a0 = *(const short8*)&xnbf[pt * 16 + l15][quad * 8];
        short8 a1 = *(const short8*)&xnbf[pt * 16 + l15][32 + quad * 8];
        const short* wb = wbf + (ot * 16 + l15) * 64;
        short8 b0 = *(const short8*)(wb + quad * 8);
        short8 b1 = *(const short8*)(wb + 32 + quad * 8);
        floatx4 c = __builtin_amdgcn_mfma_f32_16x16x32_bf16(a0, b0, zf, 0, 0, 0);
        c = __builtin_amdgcn_mfma_f32_16x16x32_bf16(a1, b1, c, 0, 0, 0);
        int oc = ot * 16 + l15;
        float bi = cb[oc];
        short4s st;
#pragma unroll
        for (int r = 0; r < 4; r++) st[r] = f2bf(c[r] + bi);
        *(short4s*)(outbf + ((size_t)b * OC + oc) * (size_t)NPIX + px0 + pt * 16 + quad * 4) = st;
    }
}

// ============ K2: dw3 (LDS-staged) + l2norm/temp + bf16 MFMA pack ==============
// grid (4, 64, NB), block 256. 16 px (one row segment) per block.
__global__ __launch_bounds__(256) void k_dw3heads(
    const short* __restrict__ qkv_pre, const float* __restrict__ dww,
    const float* __restrict__ dwb, const float* __restrict__ temp,
    short* __restrict__ Qbf, short* __restrict__ Kbf, short* __restrict__ Vbf)
{
    int px0 = blockIdx.x * 16;
    int y = blockIdx.y, b = blockIdx.z;
    int t = threadIdx.x;
    int wx0 = px0 - 8; if (wx0 < 0) wx0 = 0; if (wx0 > 32) wx0 = 32;
    int xoff = px0 - wx0;

    __shared__ short stage[3][144][40];
    __shared__ float q2[16][148];

    for (int seg = t; seg < 3 * 144 * 4; seg += 256) {
        int q = seg & 3, idx = seg >> 2;
        int c = idx % 144, r = idx / 144;
        int yy = y + r - 1;
        short8 ld = {};
        if ((unsigned)yy < 64u)
            ld = *(const short8*)(qkv_pre + (size_t)(b * 144 + c) * NPIX + yy * 64 + wx0 + q * 8);
        *(short8*)&stage[r][c][q * 8] = ld;
    }
    __syncthreads();
    int px = t & 15, g = t >> 4;
    {
        int sbase = xoff + px;
        for (int i = 0; i < 9; i++) {
            int c = g * 9 + i;
            const float* wp = dww + c * 9;
            float acc = dwb[c];
#pragma unroll
            for (int dy = 0; dy < 3; dy++) {
#pragma unroll
                for (int dx = -1; dx <= 1; dx++) {
                    int si = sbase + dx;
                    if ((unsigned)si < 32u)
                        acc += bf2f(stage[dy][c][si]) * wp[dy * 3 + dx + 1];
                }
            }
            q2[px][c] = acc;
        }
    }
    __syncthreads();
    if (t < 32) {
        int hpx = t & 15, h = t >> 4;
        int n = y * 64 + px0 + hpx;
        int bh = b * 2 + h;
        float q[24], k[24], vv[24]; float sqs = 0.f, sks = 0.f;
#pragma unroll
        for (int c = 0; c < 24; c++) {
            q[c] = q2[hpx][h * 24 + c];       sqs += q[c] * q[c];
            k[c] = q2[hpx][48 + h * 24 + c];  sks += k[c] * k[c];
            vv[c] = q2[hpx][96 + h * 24 + c];
        }
        float rq = temp[h] / fmaxf(sqrtf(sqs), 1e-12f);
        float rk = 1.f / fmaxf(sqrtf(sks), 1e-12f);
        short qs[32], ks[32];
#pragma unroll
        for (int c = 0; c < 24; c++) { qs[c] = f2bf(q[c] * rq); ks[c] = f2bf(k[c] * rk); }
#pragma unroll
        for (int c = 24; c < 32; c++) { qs[c] = 0; ks[c] = 0; }
        size_t ro = ((size_t)bh * NPIX + n) * 32;
#pragma unroll
        for (int i = 0; i < 4; i++) {
            short8 a, bb;
#pragma unroll
            for (int j = 0; j < 8; j++) { a[j] = qs[i * 8 + j]; bb[j] = ks[i * 8 + j]; }
            *(short8*)(Qbf + ro + i * 8) = a;
            *(short8*)(Kbf + ro + i * 8) = bb;
        }
        int r5 = n & 31;
        int vcol = (n & ~31) + ((r5 & 15) * 2 + (r5 >> 4));
#pragma unroll
        for (int c = 0; c < 24; c++)
            Vbf[((size_t)bh * 32 + c) * NPIX + vcol] = f2bf(vv[c]);
#pragma unroll
        for (int c = 24; c < 32; c++)
            Vbf[((size_t)bh * 32 + c) * NPIX + vcol] = 0;
    }
}

// ============ K3: MFMA flash attention, 64-key tiles, LDS double buffer ========
// grid: (qt=64, split=SPLIT, bh=4), block 256. Wave w owns q-rows qt*64+w*16..+15.
// Opart: [bh][SPLIT][32ch][4096] fp32; lpart: [bh][SPLIT][4096]
__global__ __launch_bounds__(256) void k_attn_mfma(const short* __restrict__ Qbf,
                                                   const short* __restrict__ Kbf,
                                                   const short* __restrict__ Vbf,
                                                   float* __restrict__ Opart,
                                                   float* __restrict__ lpart) {
    int qt = blockIdx.x, s = blockIdx.y, bh = blockIdx.z;
    int t = threadIdx.x;
    int w = t >> 6, lane = t & 63, l15 = lane & 15, quad = lane >> 4;

    __shared__ short tileK[2][64][40];   // rows = tile-local key (unpermuted)
    __shared__ short tileV[2][32][72];   // rows = ch, 64 permuted-key cols
    __shared__ short P[4][16][72];       // per-wave P tile, bf16

    int qrow0 = qt * 64 + w * 16;
    short8 aq = *(const short8*)(Qbf + ((size_t)bh * NPIX + qrow0 + l15) * 32 + quad * 8);

    // staging: thread t stages one K short8 and one V short8 per tile
    int krow = t >> 2, kseg = t & 3;     // 64 rows x 4 segs
    int vch = t >> 3, vseg = t & 7;      // 32 ch x 8 segs
    const short* srcK = Kbf + ((size_t)bh * NPIX + krow) * 32 + kseg * 8;
    const short* srcV = Vbf + ((size_t)(bh * 32 + vch)) * NPIX + vseg * 8;

    int key0 = s * (NPIX / SPLIT);
    *(short8*)&tileK[0][krow][kseg * 8] = *(const short8*)(srcK + (size_t)key0 * 32);
    *(short8*)&tileV[0][vch][vseg * 8]  = *(const short8*)(srcV + key0);

    floatx4 zf = {0.f, 0.f, 0.f, 0.f};
    floatx4 o0 = zf, o1 = zf;
    float ls[4] = {0.f, 0.f, 0.f, 0.f};

    const int NKT = (NPIX / SPLIT) / 64;   // 16
    for (int kt = 0; kt < NKT; kt++) {
        __syncthreads();
        int cur = kt & 1;
        short8 ldK = {}, ldV = {};
        if (kt < NKT - 1) {
            int kabs = key0 + (kt + 1) * 64;
            ldK = *(const short8*)(srcK + (size_t)kabs * 32);
            ldV = *(const short8*)(srcV + kabs);
        }
        short8 kb0 = *(const short8*)&tileK[cur][l15][quad * 8];
        short8 kb1 = *(const short8*)&tileK[cur][16 + l15][quad * 8];
        short8 kb2 = *(const short8*)&tileK[cur][32 + l15][quad * 8];
        short8 kb3 = *(const short8*)&tileK[cur][48 + l15][quad * 8];
        floatx4 s0 = __builtin_amdgcn_mfma_f32_16x16x32_bf16(aq, kb0, zf, 0, 0, 0);
        floatx4 s1 = __builtin_amdgcn_mfma_f32_16x16x32_bf16(aq, kb1, zf, 0, 0, 0);
        floatx4 s2 = __builtin_amdgcn_mfma_f32_16x16x32_bf16(aq, kb2, zf, 0, 0, 0);
        floatx4 s3 = __builtin_amdgcn_mfma_f32_16x16x32_bf16(aq, kb3, zf, 0, 0, 0);
#pragma unroll
        for (int r = 0; r < 4; r++) {
            float p0 = __expf(s0[r]);
            float p1 = __expf(s1[r]);
            float p2 = __expf(s2[r]);
            float p3 = __expf(s3[r]);
            ls[r] += (p0 + p1) + (p2 + p3);
            __hip_bfloat162 pk01 = __float22bfloat162_rn(make_float2(p0, p1));
            __hip_bfloat162 pk23 = __float22bfloat162_rn(make_float2(p2, p3));
            *(unsigned*)&P[w][quad * 4 + r][l15 * 2]      = *(unsigned*)&pk01;
            *(unsigned*)&P[w][quad * 4 + r][32 + l15 * 2] = *(unsigned*)&pk23;
        }
        short8 ap0 = *(const short8*)&P[w][l15][quad * 8];
        short8 ap1 = *(const short8*)&P[w][l15][32 + quad * 8];
        short8 vb00 = *(const short8*)&tileV[cur][l15][quad * 8];
        short8 vb01 = *(const short8*)&tileV[cur][l15][32 + quad * 8];
        short8 vb10 = *(const short8*)&tileV[cur][16 + l15][quad * 8];
        short8 vb11 = *(const short8*)&tileV[cur][16 + l15][32 + quad * 8];
        o0 = __builtin_amdgcn_mfma_f32_16x16x32_bf16(ap0, vb00, o0, 0, 0, 0);
        o0 = __builtin_amdgcn_mfma_f32_16x16x32_bf16(ap1, vb01, o0, 0, 0, 0);
        o1 = __builtin_amdgcn_mfma_f32_16x16x32_bf16(ap0, vb10, o1, 0, 0, 0);
        o1 = __builtin_amdgcn_mfma_f32_16x16x32_bf16(ap1, vb11, o1, 0, 0, 0);
        if (kt < NKT - 1) {
            *(short8*)&tileK[1 - cur][krow][kseg * 8] = ldK;
            *(short8*)&tileV[1 - cur][vch][vseg * 8]  = ldV;
        }
    }
#pragma unroll
    for (int m = 1; m < 16; m <<= 1) {
#pragma unroll
        for (int r = 0; r < 4; r++) ls[r] += __shfl_xor(ls[r], m, 64);
    }
#pragma unroll
    for (int r = 0; r < 4; r++) {
        int n = qrow0 + quad * 4 + r;
        size_t base2 = (size_t)(bh * SPLIT + s) * 32;
        Opart[(base2 + l15) * NPIX + n] = o0[r];
        Opart[(base2 + 16 + l15) * NPIX + n] = o1[r];
        if (l15 == 0) lpart[((size_t)(bh * SPLIT + s)) * NPIX + n] = ls[r];
    }
}

// ============ K4: reduce+norm + proj(MFMA)+res + LN2 + fi(MFMA) ================
// grid (128, NB), block 256. Block handles 32 px end-to-end across the seam.
__global__ __launch_bounds__(256) void k_projlnfi(
    const float* __restrict__ x, const float* __restrict__ Opart,
    const float* __restrict__ lpart, const short* __restrict__ projwbf,
    const float* __restrict__ projb,
    const float* __restrict__ n2w, const float* __restrict__ n2b,
    const short* __restrict__ fiwbf, const float* __restrict__ fib,
    float* __restrict__ x1, short* __restrict__ fp_pre)
{
    int px0 = blockIdx.x * 32;
    int b = blockIdx.y;
    int t = threadIdx.x;
    int w = t >> 6, lane = t & 63, l15 = lane & 15, quad = lane >> 4;

    __shared__ __align__(16) short Ash[32][72];
    __shared__ float rlsh[2][32];
    __shared__ float x1sh[32][53];
    __shared__ float psum[8][32], psq[8][32];
    __shared__ float muS[32], rsS[32];
    __shared__ short xnbf[32][72];

    // --- attention-output reduce + normalize -> bf16 A tile ---
    if (t < 64) {
        int h = t >> 5, px = t & 31;
        float l = 0.f;
#pragma unroll
        for (int s = 0; s < SPLIT; s++)
            l += lpart[((size_t)((b * 2 + h) * SPLIT + s)) * NPIX + px0 + px];
        rlsh[h][px] = 1.f / l;
    }
    {
        int px = t & 31, j = t >> 5;
        *(unsigned*)&Ash[px][48 + j * 2] = 0u;
        *(unsigned*)&xnbf[px][48 + j * 2] = 0u;
    }
    __syncthreads();
#pragma unroll
    for (int pi = 0; pi < 6; pi++) {
        int idx = pi * 256 + t;
        int px = idx & 31, c = idx >> 5;
        int h = c / 24, ch = c % 24;
        float acc = 0.f;
#pragma unroll
        for (int s = 0; s < SPLIT; s++)
            acc += Opart[(((size_t)((b * 2 + h) * SPLIT + s)) * 32 + ch) * NPIX + px0 + px];
        Ash[px][c] = f2bf(acc * rlsh[h][px]);
    }
    __syncthreads();
    // --- proj MFMA + residual -> x1 (global + LDS) ---
    floatx4 zf = {0.f, 0.f, 0.f, 0.f};
    for (int job = w; job < 6; job += 4) {
        int pt = job / 3, ot = job % 3;
        short8 a0 = *(const short8*)&Ash[pt * 16 + l15][quad * 8];
        short8 a1 = *(const short8*)&Ash[pt * 16 + l15][32 + quad * 8];
        const short* wb = projwbf + (ot * 16 + l15) * 64;
        short8 b0 = *(const short8*)(wb + quad * 8);
        short8 b1 = *(const short8*)(wb + 32 + quad * 8);
        floatx4 c = __builtin_amdgcn_mfma_f32_16x16x32_bf16(a0, b0, zf, 0, 0, 0);
        c = __builtin_amdgcn_mfma_f32_16x16x32_bf16(a1, b1, c, 0, 0, 0);
        int oc = ot * 16 + l15;
        float bi = projb[oc];
#pragma unroll
        for (int r = 0; r < 4; r++) {
            int px = pt * 16 + quad * 4 + r;
            size_t idx = ((size_t)b * 48 + oc) * NPIX + px0 + px;
            float val = x[idx] + c[r] + bi;
            x1[idx] = val;
            x1sh[px][oc] = val;
        }
    }
    __syncthreads();
    // --- LayerNorm2 over x1sh -> bf16 A tile ---
    int px = t & 31, g = t >> 5;
    float v[6];
    float s = 0.f, sq = 0.f;
#pragma unroll
    for (int i = 0; i < 6; i++) {
        v[i] = x1sh[px][g * 6 + i];
        s += v[i]; sq += v[i] * v[i];
    }
    psum[g][px] = s; psq[g][px] = sq;
    __syncthreads();
    if (t < 32) {
        float ss = 0.f, qq = 0.f;
#pragma unroll
        for (int i = 0; i < 8; i++) { ss += psum[i][t]; qq += psq[i][t]; }
        float mu = ss * (1.f / 48.f);
        float var = qq * (1.f / 48.f) - mu * mu;
        muS[t] = mu; rsS[t] = rsqrtf(var + 1e-5f);
    }
    __syncthreads();
    {
        float mu = muS[px], rs = rsS[px];
#pragma unroll
        for (int i = 0; i < 6; i++) {
            int c = g * 6 + i;
            xnbf[px][c] = f2bf((v[i] - mu) * rs * n2w[c] + n2b[c]);
        }
    }
    __syncthreads();
    // --- fi conv 48->192 via MFMA -> fp_pre bf16 ---
    for (int job = w; job < 24; job += 4) {
        int pt = job / 12, ot = job % 12;
        short8 a0 = *(const short8*)&xnbf[pt * 16 + l15][quad * 8];
        short8 a1 = *(const short8*)&xnbf[pt * 16 + l15][32 + quad * 8];
        const short* wb = fiwbf + (ot * 16 + l15) * 64;
        short8 b0 = *(const short8*)(wb + quad * 8);
        short8 b1 = *(const short8*)(wb + 32 + quad * 8);
        floatx4 c = __builtin_amdgcn_mfma_f32_16x16x32_bf16(a0, b0, zf, 0, 0, 0);
        c = __builtin_amdgcn_mfma_f32_16x16x32_bf16(a1, b1, c, 0, 0, 0);
        int oc = ot * 16 + l15;
        float bi = fib[oc];
        short4s st;
#pragma unroll
        for (int r = 0; r < 4; r++) st[r] = f2bf(c[r] + bi);
        *(short4s*)(fp_pre + ((size_t)b * 192 + oc) * (size_t)NPIX + px0 + pt * 16 + quad * 4) = st;
    }
}

// ============ K5: dw3 (LDS-staged) + GELU-gate + fo 1x1 (MFMA) + residual ======
// grid (4, 64, NB), block 256. 16 px per block.
__global__ __launch_bounds__(256) void k_dwgatefo(
    const short* __restrict__ fp_pre, const float* __restrict__ fdww,
    const float* __restrict__ fdwb, const short* __restrict__ fowbf,
    const float* __restrict__ fob, const float* __restrict__ x1,
    float* __restrict__ out)
{
    int px0 = blockIdx.x * 16;
    int y = blockIdx.y, b = blockIdx.z;
    int t = threadIdx.x;
    int w = t >> 6, lane = t & 63, l15 = lane & 15, quad = lane >> 4;
    int wx0 = px0 - 8; if (wx0 < 0) wx0 = 0; if (wx0 > 32) wx0 = 32;
    int xoff = px0 - wx0;

    __shared__ short stage[3][192][40];
    __shared__ short yv[16][104];

    for (int seg = t; seg < 3 * 192 * 4; seg += 256) {
        int q = seg & 3, idx = seg >> 2;
        int c = idx % 192, r = idx / 192;
        int yy = y + r - 1;
        short8 ld = {};
        if ((unsigned)yy < 64u)
            ld = *(const short8*)(fp_pre + (size_t)(b * 192 + c) * NPIX + yy * 64 + wx0 + q * 8);
        *(short8*)&stage[r][c][q * 8] = ld;
    }
    __syncthreads();
    int px = t & 15, g = t >> 4;
    {
        int sbase = xoff + px;
        for (int i = 0; i < 6; i++) {
            int c = g * 6 + i;
            const float* wp  = fdww + c * 9;
            const float* wp2 = fdww + (c + 96) * 9;
            float a  = fdwb[c];
            float g2 = fdwb[c + 96];
#pragma unroll
            for (int dy = 0; dy < 3; dy++) {
#pragma unroll
                for (int dx = -1; dx <= 1; dx++) {
                    int si = sbase + dx;
                    if ((unsigned)si < 32u) {
                        a  += bf2f(stage[dy][c][si])      * wp[dy * 3 + dx + 1];
                        g2 += bf2f(stage[dy][c + 96][si]) * wp2[dy * 3 + dx + 1];
                    }
                }
            }
            float ge = 0.5f * a * (1.f + erff(a * 0.70710678118654752f));
            yv[px][c] = f2bf(ge * g2);
        }
    }
    __syncthreads();
    if (w < 3) {
        floatx4 c = {0.f, 0.f, 0.f, 0.f};
#pragma unroll
        for (int k = 0; k < 3; k++) {
            short8 a = *(const short8*)&yv[l15][k * 32 + quad * 8];
            short8 bb = *(const short8*)(fowbf + (w * 16 + l15) * 96 + k * 32 + quad * 8);
            c = __builtin_amdgcn_mfma_f32_16x16x32_bf16(a, bb, c, 0, 0, 0);
        }
        int oc = w * 16 + l15;
        float bi = fob[oc];
#pragma unroll
        for (int r = 0; r < 4; r++) {
            int n = y * 64 + px0 + quad * 4 + r;
            size_t idx = ((size_t)b * 48 + oc) * NPIX + n;
            out[idx] = x1[idx] + c[r] + bi;
        }
    }
}

extern "C" void kernel_launch(void* const* d_in, const int* in_sizes, int n_in,
                              void* d_out, int out_size, void* d_ws, size_t ws_size,
                              hipStream_t stream) {
    const float* x       = (const float*)d_in[0];
    const float* n1w     = (const float*)d_in[1];
    const float* n1b     = (const float*)d_in[2];
    const float* qkv_w   = (const float*)d_in[3];
    const float* qkv_b   = (const float*)d_in[4];
    const float* qkvdw_w = (const float*)d_in[5];
    const float* qkvdw_b = (const float*)d_in[6];
    const float* temp    = (const float*)d_in[7];
    const float* proj_w  = (const float*)d_in[8];
    const float* proj_b  = (const float*)d_in[9];
    const float* n2w     = (const float*)d_in[10];
    const float* n2b     = (const float*)d_in[11];
    const float* fi_w    = (const float*)d_in[12];
    const float* fi_b    = (const float*)d_in[13];
    const float* fdw_w   = (const float*)d_in[14];
    const float* fdw_b   = (const float*)d_in[15];
    const float* fo_w    = (const float*)d_in[16];
    const float* fo_b    = (const float*)d_in[17];

    float* ws = (float*)d_ws;
    short* qkv_pre = (short*)ws;                       // 1,179,648 sh = 589,824 f
    short* fp_pre  = (short*)(ws + 589824);            // 1,572,864 sh = 786,432 f
    short* Qbf     = (short*)(ws + 1376256);           // 524,288 sh
    short* Kbf     = (short*)(ws + 1638400);           // 524,288 sh
    short* Vbf     = (short*)(ws + 1900544);           // 524,288 sh
    float* Opart   = ws + 2162688;                     // 4*SPLIT*32*4096 = 2,097,152 f
    float* lpart   = ws + 4259840;                     // 65,536 f
    float* x1      = ws + 4325376;                     // 393,216 f
    short* qkvwbf  = (short*)(ws + 4718592);           // 9216 sh
    short* fiwbf   = qkvwbf + 9216;                    // 12288 sh
    short* fowbf   = fiwbf + 12288;                    // 4608 sh
    short* projwbf = fowbf + 4608;                     // 3072 sh

    {   // weights -> bf16 B-layout
        int total = 144 * 64 + 192 * 64 + 48 * 96 + 48 * 64;
        k_prepw<<<(total + 255) / 256, 256, 0, stream>>>(qkv_w, fi_w, fo_w, proj_w,
                                                         qkvwbf, fiwbf, fowbf, projwbf);
    }
    {   // LN1 + qkv 1x1 (MFMA) -> qkv_pre bf16
        dim3 g(128, NB);
        k_ln_conv_mfma<<<g, 256, 0, stream>>>(x, n1w, n1b, qkvwbf, qkv_b, qkv_pre, 144);
    }
    {   // dw3 (LDS-staged) + heads pack
        dim3 g(4, 64, NB);
        k_dw3heads<<<g, 256, 0, stream>>>(qkv_pre, qkvdw_w, qkvdw_b, temp, Qbf, Kbf, Vbf);
    }
    {   // attention (64-key tiles)
        dim3 g(64, SPLIT, 4);
        k_attn_mfma<<<g, 256, 0, stream>>>(Qbf, Kbf, Vbf, Opart, lpart);
    }
    {   // reduce + proj(MFMA) + residual + LN2 + fi(MFMA)
        dim3 g(128, NB);
        k_projlnfi<<<g, 256, 0, stream>>>(x, Opart, lpart, projwbf, proj_b,
                                          n2w, n2b, fiwbf, fi_b, x1, fp_pre);
    }
    {   // dw3 (LDS-staged) + gate + fo(MFMA) + residual
        dim3 g(4, 64, NB);
        k_dwgatefo<<<g, 256, 0, stream>>>(fp_pre, fdw_w, fdw_b, fowbf, fo_b, x1,
                                          (float*)d_out);
    }
}

// Round 10
// 148.432 us; speedup vs baseline: 1.1311x; 1.0129x over previous
//
#include <hip/hip_runtime.h>
#include <hip/hip_bf16.h>
#include <math.h>

#define NPIX 4096   // 64*64
#define DIMC 48
#define NB 2
#define SPLIT 4

typedef __attribute__((ext_vector_type(8))) short short8;
typedef __attribute__((ext_vector_type(4))) short short4s;
typedef __attribute__((ext_vector_type(4))) float floatx4;

static __device__ inline short f2bf(float f) {
    union { float f; unsigned u; } v; v.f = f;
    unsigned r = (v.u + 0x7FFFu + ((v.u >> 16) & 1u)) >> 16;
    return (short)r;
}
static __device__ inline float bf2f(short s) {
    union { unsigned u; float f; } v;
    v.u = ((unsigned)(unsigned short)s) << 16;
    return v.f;
}
static __device__ inline unsigned pk2(float a, float b) {
    __hip_bfloat162 pk = __float22bfloat162_rn(make_float2(a, b));
    return *(unsigned*)&pk;
}

// ============ K0: prep bf16 B-layout weights (rows padded to 64 k, zeros) ======
__global__ void k_prepw(const float* __restrict__ qkvw, const float* __restrict__ fiw,
                        const float* __restrict__ fow, const float* __restrict__ projw,
                        short* __restrict__ qkvwbf, short* __restrict__ fiwbf,
                        short* __restrict__ fowbf, short* __restrict__ projwbf) {
    int idx = blockIdx.x * 256 + threadIdx.x;
    if (idx < 144 * 64) {
        int o = idx >> 6, c = idx & 63;
        qkvwbf[idx] = (c < 48) ? f2bf(qkvw[o * 48 + c]) : (short)0;
        return;
    }
    idx -= 144 * 64;
    if (idx < 192 * 64) {
        int o = idx >> 6, c = idx & 63;
        fiwbf[idx] = (c < 48) ? f2bf(fiw[o * 48 + c]) : (short)0;
        return;
    }
    idx -= 192 * 64;
    if (idx < 48 * 96) {
        fowbf[idx] = f2bf(fow[idx]);
        return;
    }
    idx -= 48 * 96;
    if (idx < 48 * 64) {
        int o = idx >> 6, c = idx & 63;
        projwbf[idx] = (c < 48) ? f2bf(projw[o * 48 + c]) : (short)0;
    }
}

// ============ K1: LayerNorm + 1x1 conv (MFMA), no halo =========================
// grid (128, NB), block 256. 32 px per block. out: bf16 [b][OC][4096].
__global__ __launch_bounds__(256) void k_ln_conv_mfma(
    const float* __restrict__ xin, const float* __restrict__ lw, const float* __restrict__ lb,
    const short* __restrict__ wbf, const float* __restrict__ cb,
    short* __restrict__ outbf, int OC)
{
    int px0 = blockIdx.x * 32;
    int b = blockIdx.y;
    int t = threadIdx.x;
    int w = t >> 6, lane = t & 63, l15 = lane & 15, quad = lane >> 4;

    __shared__ float psum[8][32], psq[8][32];
    __shared__ float muS[32], rsS[32];
    __shared__ short xnbf[32][72];

    int px = t & 31, g = t >> 5;     // 8 groups x 6 channels
    *(unsigned*)&xnbf[px][48 + g * 2] = 0u;

    float v[6];
    float s = 0.f, sq = 0.f;
#pragma unroll
    for (int i = 0; i < 6; i++) {
        v[i] = xin[((size_t)b * 48 + g * 6 + i) * (size_t)NPIX + px0 + px];
        s += v[i]; sq += v[i] * v[i];
    }
    psum[g][px] = s; psq[g][px] = sq;
    __syncthreads();
    if (t < 32) {
        float ss = 0.f, qq = 0.f;
#pragma unroll
        for (int i = 0; i < 8; i++) { ss += psum[i][t]; qq += psq[i][t]; }
        float mu = ss * (1.f / 48.f);
        float var = qq * (1.f / 48.f) - mu * mu;
        muS[t] = mu; rsS[t] = rsqrtf(var + 1e-5f);
    }
    __syncthreads();
    {
        float mu = muS[px], rs = rsS[px];
#pragma unroll
        for (int i = 0; i < 6; i++) {
            int c = g * 6 + i;
            xnbf[px][c] = f2bf((v[i] - mu) * rs * lw[c] + lb[c]);
        }
    }
    __syncthreads();
    floatx4 zf = {0.f, 0.f, 0.f, 0.f};
    int oct = OC >> 4;
    int njobs = 2 * oct;
    for (int job = w; job < njobs; job += 4) {
        int pt = job / oct, ot = job % oct;
        short8 a0 = *(const short8*)&xnbf[pt * 16 + l15][quad * 8];
        short8 a1 = *(const short8*)&xnbf[pt * 16 + l15][32 + quad * 8];
        const short* wb = wbf + (ot * 16 + l15) * 64;
        short8 b0 = *(const short8*)(wb + quad * 8);
        short8 b1 = *(const short8*)(wb + 32 + quad * 8);
        floatx4 c = __builtin_amdgcn_mfma_f32_16x16x32_bf16(a0, b0, zf, 0, 0, 0);
        c = __builtin_amdgcn_mfma_f32_16x16x32_bf16(a1, b1, c, 0, 0, 0);
        int oc = ot * 16 + l15;
        float bi = cb[oc];
        short4s st;
#pragma unroll
        for (int r = 0; r < 4; r++) st[r] = f2bf(c[r] + bi);
        *(short4s*)(outbf + ((size_t)b * OC + oc) * (size_t)NPIX + px0 + pt * 16 + quad * 4) = st;
    }
}

// ============ K2: dw3 (LDS-staged) + l2norm/temp + bf16 MFMA pack ==============
// grid (4, 64, NB), block 256. 16 px (one row segment) per block.
// Vbf key order within each 32-block follows pi: k<16 -> (k>>2)*8+(k&3),
// k>=16 -> ((k-16)>>2)*8+(k&3)+4  (matches PV B-fragment register order).
__global__ __launch_bounds__(256) void k_dw3heads(
    const short* __restrict__ qkv_pre, const float* __restrict__ dww,
    const float* __restrict__ dwb, const float* __restrict__ temp,
    short* __restrict__ Qbf, short* __restrict__ Kbf, short* __restrict__ Vbf)
{
    int px0 = blockIdx.x * 16;
    int y = blockIdx.y, b = blockIdx.z;
    int t = threadIdx.x;
    int wx0 = px0 - 8; if (wx0 < 0) wx0 = 0; if (wx0 > 32) wx0 = 32;
    int xoff = px0 - wx0;

    __shared__ short stage[3][144][40];
    __shared__ float q2[16][148];

    for (int seg = t; seg < 3 * 144 * 4; seg += 256) {
        int q = seg & 3, idx = seg >> 2;
        int c = idx % 144, r = idx / 144;
        int yy = y + r - 1;
        short8 ld = {};
        if ((unsigned)yy < 64u)
            ld = *(const short8*)(qkv_pre + (size_t)(b * 144 + c) * NPIX + yy * 64 + wx0 + q * 8);
        *(short8*)&stage[r][c][q * 8] = ld;
    }
    __syncthreads();
    int px = t & 15, g = t >> 4;
    {
        int sbase = xoff + px;
        for (int i = 0; i < 9; i++) {
            int c = g * 9 + i;
            const float* wp = dww + c * 9;
            float acc = dwb[c];
#pragma unroll
            for (int dy = 0; dy < 3; dy++) {
#pragma unroll
                for (int dx = -1; dx <= 1; dx++) {
                    int si = sbase + dx;
                    if ((unsigned)si < 32u)
                        acc += bf2f(stage[dy][c][si]) * wp[dy * 3 + dx + 1];
                }
            }
            q2[px][c] = acc;
        }
    }
    __syncthreads();
    if (t < 32) {
        int hpx = t & 15, h = t >> 4;
        int n = y * 64 + px0 + hpx;
        int bh = b * 2 + h;
        float q[24], k[24], vv[24]; float sqs = 0.f, sks = 0.f;
#pragma unroll
        for (int c = 0; c < 24; c++) {
            q[c] = q2[hpx][h * 24 + c];       sqs += q[c] * q[c];
            k[c] = q2[hpx][48 + h * 24 + c];  sks += k[c] * k[c];
            vv[c] = q2[hpx][96 + h * 24 + c];
        }
        float rq = temp[h] / fmaxf(sqrtf(sqs), 1e-12f);
        float rk = 1.f / fmaxf(sqrtf(sks), 1e-12f);
        short qs[32], ks[32];
#pragma unroll
        for (int c = 0; c < 24; c++) { qs[c] = f2bf(q[c] * rq); ks[c] = f2bf(k[c] * rk); }
#pragma unroll
        for (int c = 24; c < 32; c++) { qs[c] = 0; ks[c] = 0; }
        size_t ro = ((size_t)bh * NPIX + n) * 32;
#pragma unroll
        for (int i = 0; i < 4; i++) {
            short8 a, bb;
#pragma unroll
            for (int j = 0; j < 8; j++) { a[j] = qs[i * 8 + j]; bb[j] = ks[i * 8 + j]; }
            *(short8*)(Qbf + ro + i * 8) = a;
            *(short8*)(Kbf + ro + i * 8) = bb;
        }
        int r5 = n & 31;
        int pos = (r5 < 16) ? ((r5 >> 2) * 8 + (r5 & 3))
                            : (((r5 & 15) >> 2) * 8 + (r5 & 3) + 4);
        int vcol = (n & ~31) + pos;
#pragma unroll
        for (int c = 0; c < 24; c++)
            Vbf[((size_t)bh * 32 + c) * NPIX + vcol] = f2bf(vv[c]);
#pragma unroll
        for (int c = 24; c < 32; c++)
            Vbf[((size_t)bh * 32 + c) * NPIX + vcol] = 0;
    }
}

// ============ K3: MFMA flash attention, transposed-score (no P LDS round-trip) ==
// grid: (qt=64, split=SPLIT, bh=4), block 256. Wave w owns q-rows qt*64+w*16..+15.
// S^T = K·Q^T (A=K, B=Q) puts q on lanes / keys in regs; exp results pack
// directly into the PV B-fragment (out^T = V^T·P). No cross-lane transform.
// Opart: [bh][SPLIT][32ch][4096] fp32; lpart: [bh][SPLIT][4096]
__global__ __launch_bounds__(256) void k_attn_mfma(const short* __restrict__ Qbf,
                                                   const short* __restrict__ Kbf,
                                                   const short* __restrict__ Vbf,
                                                   float* __restrict__ Opart,
                                                   float* __restrict__ lpart) {
    int qt = blockIdx.x, s = blockIdx.y, bh = blockIdx.z;
    int t = threadIdx.x;
    int w = t >> 6, lane = t & 63, l15 = lane & 15, quad = lane >> 4;

    __shared__ short tileK[2][64][40];   // rows = tile-local key
    __shared__ short tileV[2][32][72];   // rows = ch, 64 pi-permuted key cols

    int qrow0 = qt * 64 + w * 16;
    // Q fragment (B operand): lane n=l15=q, regs k=d=quad*8+j
    short8 bq = *(const short8*)(Qbf + ((size_t)bh * NPIX + qrow0 + l15) * 32 + quad * 8);

    int krow = t >> 2, kseg = t & 3;     // 64 rows x 4 segs
    int vch = t >> 3, vseg = t & 7;      // 32 ch x 8 segs
    const short* srcK = Kbf + ((size_t)bh * NPIX + krow) * 32 + kseg * 8;
    const short* srcV = Vbf + ((size_t)(bh * 32 + vch)) * NPIX + vseg * 8;

    int key0 = s * (NPIX / SPLIT);
    *(short8*)&tileK[0][krow][kseg * 8] = *(const short8*)(srcK + (size_t)key0 * 32);
    *(short8*)&tileV[0][vch][vseg * 8]  = *(const short8*)(srcV + key0);

    floatx4 zf = {0.f, 0.f, 0.f, 0.f};
    floatx4 o0 = zf, o1 = zf;
    float ls = 0.f;

    const int NKT = (NPIX / SPLIT) / 64;   // 16
    for (int kt = 0; kt < NKT; kt++) {
        __syncthreads();
        int cur = kt & 1;
        short8 ldK = {}, ldV = {};
        if (kt < NKT - 1) {
            int kabs = key0 + (kt + 1) * 64;
            ldK = *(const short8*)(srcK + (size_t)kabs * 32);
            ldV = *(const short8*)(srcV + kabs);
        }
        // scores (transposed): A = K rows, B = Q
        short8 ka0 = *(const short8*)&tileK[cur][l15][quad * 8];
        short8 ka1 = *(const short8*)&tileK[cur][16 + l15][quad * 8];
        short8 ka2 = *(const short8*)&tileK[cur][32 + l15][quad * 8];
        short8 ka3 = *(const short8*)&tileK[cur][48 + l15][quad * 8];
        floatx4 s0 = __builtin_amdgcn_mfma_f32_16x16x32_bf16(ka0, bq, zf, 0, 0, 0);
        floatx4 s1 = __builtin_amdgcn_mfma_f32_16x16x32_bf16(ka1, bq, zf, 0, 0, 0);
        floatx4 s2 = __builtin_amdgcn_mfma_f32_16x16x32_bf16(ka2, bq, zf, 0, 0, 0);
        floatx4 s3 = __builtin_amdgcn_mfma_f32_16x16x32_bf16(ka3, bq, zf, 0, 0, 0);
        // exp in-register; pack into PV B-fragments (key order = pi)
        float e0[4], e1[4], e2[4], e3[4];
#pragma unroll
        for (int r = 0; r < 4; r++) {
            e0[r] = __expf(s0[r]); e1[r] = __expf(s1[r]);
            e2[r] = __expf(s2[r]); e3[r] = __expf(s3[r]);
            ls += (e0[r] + e1[r]) + (e2[r] + e3[r]);
        }
        short8 p01, p23;
        {
            unsigned* u01 = (unsigned*)&p01;
            unsigned* u23 = (unsigned*)&p23;
            u01[0] = pk2(e0[0], e0[1]); u01[1] = pk2(e0[2], e0[3]);
            u01[2] = pk2(e1[0], e1[1]); u01[3] = pk2(e1[2], e1[3]);
            u23[0] = pk2(e2[0], e2[1]); u23[1] = pk2(e2[2], e2[3]);
            u23[2] = pk2(e3[0], e3[1]); u23[3] = pk2(e3[2], e3[3]);
        }
        // PV (transposed): A = V^T (lane=ch), B = P (lane=q)
        short8 va00 = *(const short8*)&tileV[cur][l15][quad * 8];
        short8 va01 = *(const short8*)&tileV[cur][l15][32 + quad * 8];
        short8 va10 = *(const short8*)&tileV[cur][16 + l15][quad * 8];
        short8 va11 = *(const short8*)&tileV[cur][16 + l15][32 + quad * 8];
        o0 = __builtin_amdgcn_mfma_f32_16x16x32_bf16(va00, p01, o0, 0, 0, 0);
        o0 = __builtin_amdgcn_mfma_f32_16x16x32_bf16(va01, p23, o0, 0, 0, 0);
        o1 = __builtin_amdgcn_mfma_f32_16x16x32_bf16(va10, p01, o1, 0, 0, 0);
        o1 = __builtin_amdgcn_mfma_f32_16x16x32_bf16(va11, p23, o1, 0, 0, 0);
        if (kt < NKT - 1) {
            *(short8*)&tileK[1 - cur][krow][kseg * 8] = ldK;
            *(short8*)&tileV[1 - cur][vch][vseg * 8]  = ldV;
        }
    }
    // full row sum for q=l15: reduce across the 4 quads (lane bits 4,5)
    ls += __shfl_xor(ls, 16, 64);
    ls += __shfl_xor(ls, 32, 64);
    int n = qrow0 + l15;
    size_t base2 = (size_t)(bh * SPLIT + s) * 32;
#pragma unroll
    for (int r = 0; r < 4; r++) {
        Opart[(base2 + quad * 4 + r) * NPIX + n] = o0[r];
        Opart[(base2 + 16 + quad * 4 + r) * NPIX + n] = o1[r];
    }
    if (quad == 0) lpart[((size_t)(bh * SPLIT + s)) * NPIX + n] = ls;
}

// ============ K4: reduce+norm + proj(MFMA)+res + LN2 + fi(MFMA) ================
// grid (128, NB), block 256. Block handles 32 px end-to-end across the seam.
__global__ __launch_bounds__(256) void k_projlnfi(
    const float* __restrict__ x, const float* __restrict__ Opart,
    const float* __restrict__ lpart, const short* __restrict__ projwbf,
    const float* __restrict__ projb,
    const float* __restrict__ n2w, const float* __restrict__ n2b,
    const short* __restrict__ fiwbf, const float* __restrict__ fib,
    float* __restrict__ x1, short* __restrict__ fp_pre)
{
    int px0 = blockIdx.x * 32;
    int b = blockIdx.y;
    int t = threadIdx.x;
    int w = t >> 6, lane = t & 63, l15 = lane & 15, quad = lane >> 4;

    __shared__ __align__(16) short Ash[32][72];
    __shared__ float rlsh[2][32];
    __shared__ float x1sh[32][53];
    __shared__ float psum[8][32], psq[8][32];
    __shared__ float muS[32], rsS[32];
    __shared__ short xnbf[32][72];

    if (t < 64) {
        int h = t >> 5, px = t & 31;
        float l = 0.f;
#pragma unroll
        for (int s = 0; s < SPLIT; s++)
            l += lpart[((size_t)((b * 2 + h) * SPLIT + s)) * NPIX + px0 + px];
        rlsh[h][px] = 1.f / l;
    }
    {
        int px = t & 31, j = t >> 5;
        *(unsigned*)&Ash[px][48 + j * 2] = 0u;
        *(unsigned*)&xnbf[px][48 + j * 2] = 0u;
    }
    __syncthreads();
#pragma unroll
    for (int pi = 0; pi < 6; pi++) {
        int idx = pi * 256 + t;
        int px = idx & 31, c = idx >> 5;
        int h = c / 24, ch = c % 24;
        float acc = 0.f;
#pragma unroll
        for (int s = 0; s < SPLIT; s++)
            acc += Opart[(((size_t)((b * 2 + h) * SPLIT + s)) * 32 + ch) * NPIX + px0 + px];
        Ash[px][c] = f2bf(acc * rlsh[h][px]);
    }
    __syncthreads();
    floatx4 zf = {0.f, 0.f, 0.f, 0.f};
    for (int job = w; job < 6; job += 4) {
        int pt = job / 3, ot = job % 3;
        short8 a0 = *(const short8*)&Ash[pt * 16 + l15][quad * 8];
        short8 a1 = *(const short8*)&Ash[pt * 16 + l15][32 + quad * 8];
        const short* wb = projwbf + (ot * 16 + l15) * 64;
        short8 b0 = *(const short8*)(wb + quad * 8);
        short8 b1 = *(const short8*)(wb + 32 + quad * 8);
        floatx4 c = __builtin_amdgcn_mfma_f32_16x16x32_bf16(a0, b0, zf, 0, 0, 0);
        c = __builtin_amdgcn_mfma_f32_16x16x32_bf16(a1, b1, c, 0, 0, 0);
        int oc = ot * 16 + l15;
        float bi = projb[oc];
#pragma unroll
        for (int r = 0; r < 4; r++) {
            int px = pt * 16 + quad * 4 + r;
            size_t idx = ((size_t)b * 48 + oc) * NPIX + px0 + px;
            float val = x[idx] + c[r] + bi;
            x1[idx] = val;
            x1sh[px][oc] = val;
        }
    }
    __syncthreads();
    int px = t & 31, g = t >> 5;
    float v[6];
    float s = 0.f, sq = 0.f;
#pragma unroll
    for (int i = 0; i < 6; i++) {
        v[i] = x1sh[px][g * 6 + i];
        s += v[i]; sq += v[i] * v[i];
    }
    psum[g][px] = s; psq[g][px] = sq;
    __syncthreads();
    if (t < 32) {
        float ss = 0.f, qq = 0.f;
#pragma unroll
        for (int i = 0; i < 8; i++) { ss += psum[i][t]; qq += psq[i][t]; }
        float mu = ss * (1.f / 48.f);
        float var = qq * (1.f / 48.f) - mu * mu;
        muS[t] = mu; rsS[t] = rsqrtf(var + 1e-5f);
    }
    __syncthreads();
    {
        float mu = muS[px], rs = rsS[px];
#pragma unroll
        for (int i = 0; i < 6; i++) {
            int c = g * 6 + i;
            xnbf[px][c] = f2bf((v[i] - mu) * rs * n2w[c] + n2b[c]);
        }
    }
    __syncthreads();
    for (int job = w; job < 24; job += 4) {
        int pt = job / 12, ot = job % 12;
        short8 a0 = *(const short8*)&xnbf[pt * 16 + l15][quad * 8];
        short8 a1 = *(const short8*)&xnbf[pt * 16 + l15][32 + quad * 8];
        const short* wb = fiwbf + (ot * 16 + l15) * 64;
        short8 b0 = *(const short8*)(wb + quad * 8);
        short8 b1 = *(const short8*)(wb + 32 + quad * 8);
        floatx4 c = __builtin_amdgcn_mfma_f32_16x16x32_bf16(a0, b0, zf, 0, 0, 0);
        c = __builtin_amdgcn_mfma_f32_16x16x32_bf16(a1, b1, c, 0, 0, 0);
        int oc = ot * 16 + l15;
        float bi = fib[oc];
        short4s st;
#pragma unroll
        for (int r = 0; r < 4; r++) st[r] = f2bf(c[r] + bi);
        *(short4s*)(fp_pre + ((size_t)b * 192 + oc) * (size_t)NPIX + px0 + pt * 16 + quad * 4) = st;
    }
}

// ============ K5: dw3 (LDS-staged) + GELU-gate + fo 1x1 (MFMA) + residual ======
// grid (4, 64, NB), block 256. 16 px per block.
__global__ __launch_bounds__(256) void k_dwgatefo(
    const short* __restrict__ fp_pre, const float* __restrict__ fdww,
    const float* __restrict__ fdwb, const short* __restrict__ fowbf,
    const float* __restrict__ fob, const float* __restrict__ x1,
    float* __restrict__ out)
{
    int px0 = blockIdx.x * 16;
    int y = blockIdx.y, b = blockIdx.z;
    int t = threadIdx.x;
    int w = t >> 6, lane = t & 63, l15 = lane & 15, quad = lane >> 4;
    int wx0 = px0 - 8; if (wx0 < 0) wx0 = 0; if (wx0 > 32) wx0 = 32;
    int xoff = px0 - wx0;

    __shared__ short stage[3][192][40];
    __shared__ short yv[16][104];

    for (int seg = t; seg < 3 * 192 * 4; seg += 256) {
        int q = seg & 3, idx = seg >> 2;
        int c = idx % 192, r = idx / 192;
        int yy = y + r - 1;
        short8 ld = {};
        if ((unsigned)yy < 64u)
            ld = *(const short8*)(fp_pre + (size_t)(b * 192 + c) * NPIX + yy * 64 + wx0 + q * 8);
        *(short8*)&stage[r][c][q * 8] = ld;
    }
    __syncthreads();
    int px = t & 15, g = t >> 4;
    {
        int sbase = xoff + px;
        for (int i = 0; i < 6; i++) {
            int c = g * 6 + i;
            const float* wp  = fdww + c * 9;
            const float* wp2 = fdww + (c + 96) * 9;
            float a  = fdwb[c];
            float g2 = fdwb[c + 96];
#pragma unroll
            for (int dy = 0; dy < 3; dy++) {
#pragma unroll
                for (int dx = -1; dx <= 1; dx++) {
                    int si = sbase + dx;
                    if ((unsigned)si < 32u) {
                        a  += bf2f(stage[dy][c][si])      * wp[dy * 3 + dx + 1];
                        g2 += bf2f(stage[dy][c + 96][si]) * wp2[dy * 3 + dx + 1];
                    }
                }
            }
            float ge = 0.5f * a * (1.f + erff(a * 0.70710678118654752f));
            yv[px][c] = f2bf(ge * g2);
        }
    }
    __syncthreads();
    if (w < 3) {
        floatx4 c = {0.f, 0.f, 0.f, 0.f};
#pragma unroll
        for (int k = 0; k < 3; k++) {
            short8 a = *(const short8*)&yv[l15][k * 32 + quad * 8];
            short8 bb = *(const short8*)(fowbf + (w * 16 + l15) * 96 + k * 32 + quad * 8);
            c = __builtin_amdgcn_mfma_f32_16x16x32_bf16(a, bb, c, 0, 0, 0);
        }
        int oc = w * 16 + l15;
        float bi = fob[oc];
#pragma unroll
        for (int r = 0; r < 4; r++) {
            int n = y * 64 + px0 + quad * 4 + r;
            size_t idx = ((size_t)b * 48 + oc) * NPIX + n;
            out[idx] = x1[idx] + c[r] + bi;
        }
    }
}

extern "C" void kernel_launch(void* const* d_in, const int* in_sizes, int n_in,
                              void* d_out, int out_size, void* d_ws, size_t ws_size,
                              hipStream_t stream) {
    const float* x       = (const float*)d_in[0];
    const float* n1w     = (const float*)d_in[1];
    const float* n1b     = (const float*)d_in[2];
    const float* qkv_w   = (const float*)d_in[3];
    const float* qkv_b   = (const float*)d_in[4];
    const float* qkvdw_w = (const float*)d_in[5];
    const float* qkvdw_b = (const float*)d_in[6];
    const float* temp    = (const float*)d_in[7];
    const float* proj_w  = (const float*)d_in[8];
    const float* proj_b  = (const float*)d_in[9];
    const float* n2w     = (const float*)d_in[10];
    const float* n2b     = (const float*)d_in[11];
    const float* fi_w    = (const float*)d_in[12];
    const float* fi_b    = (const float*)d_in[13];
    const float* fdw_w   = (const float*)d_in[14];
    const float* fdw_b   = (const float*)d_in[15];
    const float* fo_w    = (const float*)d_in[16];
    const float* fo_b    = (const float*)d_in[17];

    float* ws = (float*)d_ws;
    short* qkv_pre = (short*)ws;                       // 1,179,648 sh = 589,824 f
    short* fp_pre  = (short*)(ws + 589824);            // 1,572,864 sh = 786,432 f
    short* Qbf     = (short*)(ws + 1376256);           // 524,288 sh
    short* Kbf     = (short*)(ws + 1638400);           // 524,288 sh
    short* Vbf     = (short*)(ws + 1900544);           // 524,288 sh
    float* Opart   = ws + 2162688;                     // 4*SPLIT*32*4096 = 2,097,152 f
    float* lpart   = ws + 4259840;                     // 65,536 f
    float* x1      = ws + 4325376;                     // 393,216 f
    short* qkvwbf  = (short*)(ws + 4718592);           // 9216 sh
    short* fiwbf   = qkvwbf + 9216;                    // 12288 sh
    short* fowbf   = fiwbf + 12288;                    // 4608 sh
    short* projwbf = fowbf + 4608;                     // 3072 sh

    {   // weights -> bf16 B-layout
        int total = 144 * 64 + 192 * 64 + 48 * 96 + 48 * 64;
        k_prepw<<<(total + 255) / 256, 256, 0, stream>>>(qkv_w, fi_w, fo_w, proj_w,
                                                         qkvwbf, fiwbf, fowbf, projwbf);
    }
    {   // LN1 + qkv 1x1 (MFMA) -> qkv_pre bf16
        dim3 g(128, NB);
        k_ln_conv_mfma<<<g, 256, 0, stream>>>(x, n1w, n1b, qkvwbf, qkv_b, qkv_pre, 144);
    }
    {   // dw3 (LDS-staged) + heads pack
        dim3 g(4, 64, NB);
        k_dw3heads<<<g, 256, 0, stream>>>(qkv_pre, qkvdw_w, qkvdw_b, temp, Qbf, Kbf, Vbf);
    }
    {   // attention (transposed-score, register P)
        dim3 g(64, SPLIT, 4);
        k_attn_mfma<<<g, 256, 0, stream>>>(Qbf, Kbf, Vbf, Opart, lpart);
    }
    {   // reduce + proj(MFMA) + residual + LN2 + fi(MFMA)
        dim3 g(128, NB);
        k_projlnfi<<<g, 256, 0, stream>>>(x, Opart, lpart, projwbf, proj_b,
                                          n2w, n2b, fiwbf, fi_b, x1, fp_pre);
    }
    {   // dw3 (LDS-staged) + gate + fo(MFMA) + residual
        dim3 g(4, 64, NB);
        k_dwgatefo<<<g, 256, 0, stream>>>(fp_pre, fdw_w, fdw_b, fowbf, fo_b, x1,
                                          (float*)d_out);
    }
}